// Round 1
// baseline (1203.805 us; speedup 1.0000x reference)
//
#include <hip/hip_runtime.h>
#include <hip/hip_bf16.h>

// Problem constants
#define BB 4
#define HH 8
#define SS 2048
#define HD 80
#define CC 128
#define NC 16
#define DH 480           // MULT*HD
#define NROW (BB*HH*SS)  // 65536
#define ROWSZ ((size_t)NROW * HD)  // 5,242,880 floats per tensor buffer

// ---------------------------------------------------------------------------
// Kernel 1: first LN (x reshaped is a pure reinterpret: row = (b*8+h)*2048+s)
// one wave (64 lanes) per 80-wide row; 4 rows per 256-thread block
__global__ __launch_bounds__(256) void k_ln0(const float* __restrict__ x,
                                             const float* __restrict__ g,
                                             const float* __restrict__ be,
                                             float* __restrict__ hdn,
                                             float* __restrict__ res) {
    int row  = blockIdx.x * 4 + (threadIdx.x >> 6);
    int lane = threadIdx.x & 63;
    const float* xr = x + (size_t)row * HD;
    float v0 = xr[lane];
    float v1 = (lane < 16) ? xr[64 + lane] : 0.f;
    float s  = v0 + v1;
    float sq = v0 * v0 + v1 * v1;
#pragma unroll
    for (int o = 32; o; o >>= 1) { s += __shfl_xor(s, o); sq += __shfl_xor(sq, o); }
    float m    = s * (1.f / 80.f);
    float var  = sq * (1.f / 80.f) - m * m;
    float rstd = rsqrtf(var + 1e-5f);
    size_t base = (size_t)row * HD;
    float y0 = (v0 - m) * rstd * g[lane] + be[lane];
    hdn[base + lane] = y0; res[base + lane] = y0;
    if (lane < 16) {
        float y1 = (v1 - m) * rstd * g[64 + lane] + be[64 + lane];
        hdn[base + 64 + lane] = y1; res[base + 64 + lane] = y1;
    }
}

// ---------------------------------------------------------------------------
// Kernel 2: per-chunk intra attention + chunk KV outer product.
// grid = B*H*NC = 512 blocks, 256 threads. q = k = v = hdn (single LDS copy).
__global__ __launch_bounds__(256) void k_attn_a(const float* __restrict__ hdn,
                                                const float* __restrict__ slopes,
                                                float* __restrict__ oin,
                                                float* __restrict__ ckv) {
    __shared__ float X[CC][HD + 1];   // 128x81  (pad breaks bank conflicts)
    __shared__ float SC[CC][33];      // 128x32 score tile (+pad)
    __shared__ float qd[CC], ek[CC], kd[CC];

    int t  = threadIdx.x;
    int bk = blockIdx.x;         // 0..511
    int bh = bk >> 4;
    int n  = bk & 15;
    int h  = bh & 7;
    float sl = slopes[h];

    const float* xb = hdn + ((size_t)bh * SS + (size_t)n * CC) * HD;
    for (int u = t; u < CC * HD; u += 256) {
        int i = u / HD, k = u - i * HD;
        X[i][k] = xb[u];
    }
    if (t < CC) {
        qd[t] = expf(-sl * (float)t);            // decay of query vs chunk start
        ek[t] = expf( sl * (float)t);            // so qd[i]*ek[j] = exp(-s*(i-j))
        kd[t] = expf(-sl * (float)(CC - t));     // key decay to next chunk start
    }
    __syncthreads();

    // output accumulators: each thread owns row i_o = t>>1, 40 of 80 dims
    int i_o   = t >> 1;
    int dbase = (t & 1) * 40;
    float oacc[40];
#pragma unroll
    for (int m = 0; m < 40; ++m) oacc[m] = 0.f;

    int ig = t >> 3;   // 0..31 -> rows ig*4 .. +3
    int jg = t & 7;    // 0..7  -> cols jg*4 .. +3 within tile

    for (int jt = 0; jt < 4; ++jt) {
        int j0 = jt * 32;
        // score tile: SC[i][jj] = (i>=j) * exp(-s*(i-j)) * dot(x_i, x_j)
        float acc[4][4];
#pragma unroll
        for (int a = 0; a < 4; ++a)
#pragma unroll
            for (int b = 0; b < 4; ++b) acc[a][b] = 0.f;
        for (int k = 0; k < HD; ++k) {
            float xa[4], xv[4];
#pragma unroll
            for (int a = 0; a < 4; ++a) xa[a] = X[ig * 4 + a][k];
#pragma unroll
            for (int b = 0; b < 4; ++b) xv[b] = X[j0 + jg * 4 + b][k];
#pragma unroll
            for (int a = 0; a < 4; ++a)
#pragma unroll
                for (int b = 0; b < 4; ++b) acc[a][b] += xa[a] * xv[b];
        }
#pragma unroll
        for (int a = 0; a < 4; ++a)
#pragma unroll
            for (int b = 0; b < 4; ++b) {
                int i = ig * 4 + a, j = j0 + jg * 4 + b;
                float f = (i >= j) ? qd[i] * ek[j] : 0.f;
                SC[i][jg * 4 + b] = acc[a][b] * f;
            }
        __syncthreads();
        // o += SC_tile @ V_tile
        for (int jj = 0; jj < 32; ++jj) {
            float scv = SC[i_o][jj];
            const float* xrow = &X[j0 + jj][dbase];
#pragma unroll
            for (int m = 0; m < 40; ++m) oacc[m] += scv * xrow[m];
        }
        __syncthreads();
    }
    float* orow = oin + ((size_t)bh * SS + (size_t)n * CC + i_o) * HD + dbase;
#pragma unroll
    for (int m = 0; m < 40; ++m) orow[m] = oacc[m];

    // chunk KV: kv[e][d] = sum_j kd[j] * X[j][e] * X[j][d]
    int eg = t >> 4;   // 0..15 -> e = eg*5 + a
    int dg = t & 15;   // 0..15 -> d = dg*5 + b
    float ka[5][5];
#pragma unroll
    for (int a = 0; a < 5; ++a)
#pragma unroll
        for (int b = 0; b < 5; ++b) ka[a][b] = 0.f;
    for (int j = 0; j < CC; ++j) {
        float kdj = kd[j];
        float xe[5], xd[5];
#pragma unroll
        for (int a = 0; a < 5; ++a) xe[a] = X[j][eg * 5 + a] * kdj;
#pragma unroll
        for (int b = 0; b < 5; ++b) xd[b] = X[j][dg * 5 + b];
#pragma unroll
        for (int a = 0; a < 5; ++a)
#pragma unroll
            for (int b = 0; b < 5; ++b) ka[a][b] += xe[a] * xd[b];
    }
    float* kvout = ckv + (size_t)bk * (HD * HD);
#pragma unroll
    for (int a = 0; a < 5; ++a)
#pragma unroll
        for (int b = 0; b < 5; ++b)
            kvout[(eg * 5 + a) * HD + dg * 5 + b] = ka[a][b];
}

// ---------------------------------------------------------------------------
// Kernel 3: in-place decay prefix-scan over chunk KVs.
// After this, kv[bh][n] holds the KV *state at the start of chunk n*.
__global__ __launch_bounds__(256) void k_scan(float* __restrict__ kv,
                                              const float* __restrict__ slopes) {
    int idx = blockIdx.x * 256 + threadIdx.x;   // < 32*6400
    int bh  = idx / (HD * HD);
    int ed  = idx - bh * (HD * HD);
    float bd = expf(-slopes[bh & 7] * (float)CC);
    size_t base = (size_t)bh * NC * (HD * HD) + ed;
    float st = 0.f;
#pragma unroll
    for (int n = 0; n < NC; ++n) {
        size_t p = base + (size_t)n * (HD * HD);
        float cv = kv[p];
        kv[p] = st;
        st = bd * st + cv;
    }
}

// ---------------------------------------------------------------------------
// Kernel 4: inter-chunk term + intra + residual + LN (fused). One wave/row.
__global__ __launch_bounds__(256) void k_attn_b(const float* __restrict__ hdn_in,
                                                const float* __restrict__ oin,
                                                const float* __restrict__ kvs,
                                                const float* __restrict__ res,
                                                const float* __restrict__ slopes,
                                                const float* __restrict__ g,
                                                const float* __restrict__ be,
                                                float* __restrict__ hdn_out) {
    int row  = blockIdx.x * 4 + (threadIdx.x >> 6);
    int lane = threadIdx.x & 63;
    int bh   = row >> 11;          // /2048
    int h    = bh & 7;
    int sp   = row & 2047;
    int n    = sp >> 7;
    int i    = sp & 127;
    float qdec = expf(-slopes[h] * (float)i);

    size_t base = (size_t)row * HD;
    float q0 = hdn_in[base + lane];
    float q1 = (lane < 16) ? hdn_in[base + 64 + lane] : 0.f;

    const float* KV = kvs + ((size_t)bh * NC + n) * (HD * HD);
    float a0 = 0.f, a1 = 0.f;
    for (int e = 0; e < HD; ++e) {
        float qe = (e < 64) ? __shfl(q0, e) : __shfl(q1, e - 64);
        a0 += qe * KV[e * HD + lane];
        if (lane < 16) a1 += qe * KV[e * HD + 64 + lane];
    }
    float t0 = oin[base + lane] + qdec * a0 + res[base + lane];
    float t1 = 0.f;
    if (lane < 16) t1 = oin[base + 64 + lane] + qdec * a1 + res[base + 64 + lane];

    float s  = t0 + t1;
    float sq = t0 * t0 + t1 * t1;
#pragma unroll
    for (int o = 32; o; o >>= 1) { s += __shfl_xor(s, o); sq += __shfl_xor(sq, o); }
    float m    = s * (1.f / 80.f);
    float var  = sq * (1.f / 80.f) - m * m;
    float rstd = rsqrtf(var + 1e-5f);
    hdn_out[base + lane] = (t0 - m) * rstd * g[lane] + be[lane];
    if (lane < 16)
        hdn_out[base + 64 + lane] = (t1 - m) * rstd * g[64 + lane] + be[64 + lane];
}

// ---------------------------------------------------------------------------
// Kernel 5: FFN (80 -> 480 leaky-relu -> 80) + residual + LN, fused.
// One block = 32 rows. Hidden dim tiled by 96; W1/W2 tiles share one LDS buf.
__global__ __launch_bounds__(256) void k_ffn(const float* __restrict__ hdn_in,
                                             const float* __restrict__ W1,
                                             const float* __restrict__ b1,
                                             const float* __restrict__ W2,
                                             const float* __restrict__ b2,
                                             const float* __restrict__ res,
                                             const float* __restrict__ g,
                                             const float* __restrict__ be,
                                             float* __restrict__ hdn_out) {
    __shared__ float Xs[32][HD + 1];     // 32x81
    __shared__ float Ws[HD * 96];        // union: W1 tile (80x96) / W2 tile (96x80)
    __shared__ float Hs[32][97];         // hidden tile (+pad)

    int t = threadIdx.x;
    size_t rowbase = (size_t)blockIdx.x * 32;

    for (int u = t; u < 32 * HD; u += 256) {
        int i = u / HD, k = u - i * HD;
        Xs[i][k] = hdn_in[(rowbase + i) * HD + k];
    }

    int oi = (t >> 4) * 2;     // output rows {oi, oi+1}
    int od = (t & 15) * 5;     // output dims {od .. od+4}
    int hi = (t >> 4) * 2;     // hidden rows
    int hj = (t & 15) * 6;     // hidden cols {hj .. hj+5} within tile
    float acc[2][5];
#pragma unroll
    for (int a = 0; a < 2; ++a)
#pragma unroll
        for (int m = 0; m < 5; ++m) acc[a][m] = 0.f;

    for (int jt = 0; jt < DH; jt += 96) {
        __syncthreads();                       // prev tile fully consumed (also covers Xs load)
        for (int u = t; u < HD * 96; u += 256) {
            int k = u / 96, jj = u - k * 96;
            Ws[u] = W1[k * DH + jt + jj];
        }
        __syncthreads();
        // hidden tile
        float ha[2][6];
#pragma unroll
        for (int a = 0; a < 2; ++a)
#pragma unroll
            for (int b = 0; b < 6; ++b) ha[a][b] = 0.f;
        for (int k = 0; k < HD; ++k) {
            float x0 = Xs[hi][k], x1 = Xs[hi + 1][k];
#pragma unroll
            for (int b = 0; b < 6; ++b) {
                float w = Ws[k * 96 + hj + b];
                ha[0][b] += x0 * w;
                ha[1][b] += x1 * w;
            }
        }
#pragma unroll
        for (int a = 0; a < 2; ++a)
#pragma unroll
            for (int b = 0; b < 6; ++b) {
                float v = ha[a][b] + b1[jt + hj + b];
                Hs[hi + a][hj + b] = (v > 0.f) ? v : 0.01f * v;
            }
        __syncthreads();
        // W2 tile (reuse Ws)
        for (int u = t; u < 96 * HD; u += 256) {
            int jj = u / HD, d = u - jj * HD;
            Ws[u] = W2[(jt + jj) * HD + d];
        }
        __syncthreads();
        for (int jj = 0; jj < 96; ++jj) {
            float h0 = Hs[oi][jj], h1 = Hs[oi + 1][jj];
#pragma unroll
            for (int m = 0; m < 5; ++m) {
                float w = Ws[jj * HD + od + m];
                acc[0][m] += h0 * w;
                acc[1][m] += h1 * w;
            }
        }
    }

    // + b2 + residual, then LN per row (16 lanes per row, 5 dims each)
    float tv[2][5];
#pragma unroll
    for (int a = 0; a < 2; ++a)
#pragma unroll
        for (int m = 0; m < 5; ++m)
            tv[a][m] = acc[a][m] + b2[od + m] + res[(rowbase + oi + a) * HD + od + m];

#pragma unroll
    for (int a = 0; a < 2; ++a) {
        float s = 0.f, sq = 0.f;
#pragma unroll
        for (int m = 0; m < 5; ++m) { s += tv[a][m]; sq += tv[a][m] * tv[a][m]; }
#pragma unroll
        for (int o = 8; o; o >>= 1) { s += __shfl_xor(s, o); sq += __shfl_xor(sq, o); }
        float mn   = s * (1.f / 80.f);
        float var  = sq * (1.f / 80.f) - mn * mn;
        float rstd = rsqrtf(var + 1e-5f);
#pragma unroll
        for (int m = 0; m < 5; ++m)
            hdn_out[(rowbase + oi + a) * HD + od + m] =
                (tv[a][m] - mn) * rstd * g[od + m] + be[od + m];
    }
}

// ---------------------------------------------------------------------------
// Kernel 6: mean over heads -> (B, S, HD)
__global__ __launch_bounds__(256) void k_mean(const float* __restrict__ hdn,
                                              float* __restrict__ out) {
    int idx = blockIdx.x * 256 + threadIdx.x;   // < 4*2048*80
    int b   = idx / (SS * HD);
    int sd  = idx - b * (SS * HD);
    float s = 0.f;
#pragma unroll
    for (int h = 0; h < HH; ++h)
        s += hdn[((size_t)(b * HH + h)) * (SS * HD) + sd];
    out[idx] = s * 0.125f;
}

// ---------------------------------------------------------------------------
extern "C" void kernel_launch(void* const* d_in, const int* in_sizes, int n_in,
                              void* d_out, int out_size, void* d_ws, size_t ws_size,
                              hipStream_t stream) {
    (void)in_sizes; (void)n_in; (void)out_size; (void)ws_size;
    const float* x      = (const float*)d_in[0];
    const float* W1     = (const float*)d_in[1];
    const float* b1     = (const float*)d_in[2];
    const float* W2     = (const float*)d_in[3];
    const float* b2     = (const float*)d_in[4];
    const float* gamma  = (const float*)d_in[5];
    const float* beta   = (const float*)d_in[6];
    const float* slopes = (const float*)d_in[7];
    float* out = (float*)d_out;
    float* ws  = (float*)d_ws;

    float* res = ws;                 // 5,242,880 floats
    float* hdn = ws + ROWSZ;         // 5,242,880
    float* oin = ws + 2 * ROWSZ;     // 5,242,880
    float* kv  = ws + 3 * ROWSZ;     // 32*16*6400 = 3,276,800  (ckv -> scanned states)

    k_ln0<<<NROW / 4, 256, 0, stream>>>(x, gamma, beta, hdn, res);
    for (int it = 0; it < 2; ++it) {
        k_attn_a<<<BB * HH * NC, 256, 0, stream>>>(hdn, slopes, oin, kv);
        k_scan<<<(BB * HH * HD * HD) / 256, 256, 0, stream>>>(kv, slopes);
        k_attn_b<<<NROW / 4, 256, 0, stream>>>(hdn, oin, kv, res, slopes, gamma, beta, hdn);
        k_ffn<<<NROW / 32, 256, 0, stream>>>(hdn, W1, b1, W2, b2, res, gamma, beta, hdn);
    }
    k_mean<<<(BB * SS * HD) / 256, 256, 0, stream>>>(hdn, out);
}

// Round 2
// 896.208 us; speedup vs baseline: 1.3432x; 1.3432x over previous
//
#include <hip/hip_runtime.h>
#include <hip/hip_bf16.h>

// Problem constants
#define BB 4
#define HH 8
#define SS 2048
#define HD 80
#define CC 128
#define NC 16
#define DH 480           // MULT*HD
#define NROW (BB*HH*SS)  // 65536
#define ROWSZ ((size_t)NROW * HD)  // 5,242,880 floats per tensor buffer

typedef unsigned short ushortT;
typedef __attribute__((ext_vector_type(8))) short bfrag;   // 8 bf16 = 4 VGPRs
typedef __attribute__((ext_vector_type(4))) float f4;

__device__ __forceinline__ ushortT f2bf(float f) {
    __hip_bfloat16 h = __float2bfloat16(f);   // RNE
    ushortT u; __builtin_memcpy(&u, &h, 2); return u;
}

// ---------------------------------------------------------------------------
// Kernel 0: prep — transpose + bf16-cast W1 (-> W1T[480][96], K zero-padded)
// and W2 (-> W2T[80][480]). Runs once per launch; outputs live in d_out tail
// (safe: k_mean overwrites d_out only at the very end).
__global__ __launch_bounds__(256) void k_prep(const float* __restrict__ W1,
                                              const float* __restrict__ W2,
                                              ushortT* __restrict__ W1T,
                                              ushortT* __restrict__ W2T) {
    int idx = blockIdx.x * 256 + threadIdx.x;
    if (idx < 480 * 96) {
        int n = idx / 96, k = idx - n * 96;
        float v = (k < HD) ? W1[k * DH + n] : 0.f;
        W1T[idx] = f2bf(v);
    } else if (idx < 480 * 96 + 80 * 480) {
        int j = idx - 480 * 96;
        int n = j / DH, k = j - n * DH;
        W2T[j] = f2bf(W2[k * HD + n]);
    }
}

// ---------------------------------------------------------------------------
// Kernel 1: first LN (x reshaped is a pure reinterpret: row = (b*8+h)*2048+s)
__global__ __launch_bounds__(256) void k_ln0(const float* __restrict__ x,
                                             const float* __restrict__ g,
                                             const float* __restrict__ be,
                                             float* __restrict__ hdn,
                                             float* __restrict__ res) {
    int row  = blockIdx.x * 4 + (threadIdx.x >> 6);
    int lane = threadIdx.x & 63;
    const float* xr = x + (size_t)row * HD;
    float v0 = xr[lane];
    float v1 = (lane < 16) ? xr[64 + lane] : 0.f;
    float s  = v0 + v1;
    float sq = v0 * v0 + v1 * v1;
#pragma unroll
    for (int o = 32; o; o >>= 1) { s += __shfl_xor(s, o); sq += __shfl_xor(sq, o); }
    float m    = s * (1.f / 80.f);
    float var  = sq * (1.f / 80.f) - m * m;
    float rstd = rsqrtf(var + 1e-5f);
    size_t base = (size_t)row * HD;
    float y0 = (v0 - m) * rstd * g[lane] + be[lane];
    hdn[base + lane] = y0; res[base + lane] = y0;
    if (lane < 16) {
        float y1 = (v1 - m) * rstd * g[64 + lane] + be[64 + lane];
        hdn[base + 64 + lane] = y1; res[base + 64 + lane] = y1;
    }
}

// ---------------------------------------------------------------------------
// Kernel 2: per-chunk intra attention + chunk KV outer product (fp32).
__global__ __launch_bounds__(256) void k_attn_a(const float* __restrict__ hdn,
                                                const float* __restrict__ slopes,
                                                float* __restrict__ oin,
                                                float* __restrict__ ckv) {
    __shared__ float X[CC][HD + 1];
    __shared__ float SC[CC][33];
    __shared__ float qd[CC], ek[CC], kd[CC];

    int t  = threadIdx.x;
    int bk = blockIdx.x;
    int bh = bk >> 4;
    int n  = bk & 15;
    int h  = bh & 7;
    float sl = slopes[h];

    const float* xb = hdn + ((size_t)bh * SS + (size_t)n * CC) * HD;
    for (int u = t; u < CC * HD; u += 256) {
        int i = u / HD, k = u - i * HD;
        X[i][k] = xb[u];
    }
    if (t < CC) {
        qd[t] = expf(-sl * (float)t);
        ek[t] = expf( sl * (float)t);
        kd[t] = expf(-sl * (float)(CC - t));
    }
    __syncthreads();

    int i_o   = t >> 1;
    int dbase = (t & 1) * 40;
    float oacc[40];
#pragma unroll
    for (int m = 0; m < 40; ++m) oacc[m] = 0.f;

    int ig = t >> 3;
    int jg = t & 7;

    for (int jt = 0; jt < 4; ++jt) {
        int j0 = jt * 32;
        float acc[4][4];
#pragma unroll
        for (int a = 0; a < 4; ++a)
#pragma unroll
            for (int b = 0; b < 4; ++b) acc[a][b] = 0.f;
        for (int k = 0; k < HD; ++k) {
            float xa[4], xv[4];
#pragma unroll
            for (int a = 0; a < 4; ++a) xa[a] = X[ig * 4 + a][k];
#pragma unroll
            for (int b = 0; b < 4; ++b) xv[b] = X[j0 + jg * 4 + b][k];
#pragma unroll
            for (int a = 0; a < 4; ++a)
#pragma unroll
                for (int b = 0; b < 4; ++b) acc[a][b] += xa[a] * xv[b];
        }
#pragma unroll
        for (int a = 0; a < 4; ++a)
#pragma unroll
            for (int b = 0; b < 4; ++b) {
                int i = ig * 4 + a, j = j0 + jg * 4 + b;
                float f = (i >= j) ? qd[i] * ek[j] : 0.f;
                SC[i][jg * 4 + b] = acc[a][b] * f;
            }
        __syncthreads();
        for (int jj = 0; jj < 32; ++jj) {
            float scv = SC[i_o][jj];
            const float* xrow = &X[j0 + jj][dbase];
#pragma unroll
            for (int m = 0; m < 40; ++m) oacc[m] += scv * xrow[m];
        }
        __syncthreads();
    }
    float* orow = oin + ((size_t)bh * SS + (size_t)n * CC + i_o) * HD + dbase;
#pragma unroll
    for (int m = 0; m < 40; ++m) orow[m] = oacc[m];

    int eg = t >> 4;
    int dg = t & 15;
    float ka[5][5];
#pragma unroll
    for (int a = 0; a < 5; ++a)
#pragma unroll
        for (int b = 0; b < 5; ++b) ka[a][b] = 0.f;
    for (int j = 0; j < CC; ++j) {
        float kdj = kd[j];
        float xe[5], xd[5];
#pragma unroll
        for (int a = 0; a < 5; ++a) xe[a] = X[j][eg * 5 + a] * kdj;
#pragma unroll
        for (int b = 0; b < 5; ++b) xd[b] = X[j][dg * 5 + b];
#pragma unroll
        for (int a = 0; a < 5; ++a)
#pragma unroll
            for (int b = 0; b < 5; ++b) ka[a][b] += xe[a] * xd[b];
    }
    float* kvout = ckv + (size_t)bk * (HD * HD);
#pragma unroll
    for (int a = 0; a < 5; ++a)
#pragma unroll
        for (int b = 0; b < 5; ++b)
            kvout[(eg * 5 + a) * HD + dg * 5 + b] = ka[a][b];
}

// ---------------------------------------------------------------------------
// Kernel 3: in-place decay prefix-scan over chunk KVs.
__global__ __launch_bounds__(256) void k_scan(float* __restrict__ kv,
                                              const float* __restrict__ slopes) {
    int idx = blockIdx.x * 256 + threadIdx.x;
    int bh  = idx / (HD * HD);
    int ed  = idx - bh * (HD * HD);
    float bd = expf(-slopes[bh & 7] * (float)CC);
    size_t base = (size_t)bh * NC * (HD * HD) + ed;
    float st = 0.f;
#pragma unroll
    for (int n = 0; n < NC; ++n) {
        size_t p = base + (size_t)n * (HD * HD);
        float cv = kv[p];
        kv[p] = st;
        st = bd * st + cv;
    }
}

// ---------------------------------------------------------------------------
// Kernel 4: inter-chunk term + intra + residual + LN (fused). One wave/row.
__global__ __launch_bounds__(256) void k_attn_b(const float* __restrict__ hdn_in,
                                                const float* __restrict__ oin,
                                                const float* __restrict__ kvs,
                                                const float* __restrict__ res,
                                                const float* __restrict__ slopes,
                                                const float* __restrict__ g,
                                                const float* __restrict__ be,
                                                float* __restrict__ hdn_out) {
    int row  = blockIdx.x * 4 + (threadIdx.x >> 6);
    int lane = threadIdx.x & 63;
    int bh   = row >> 11;
    int h    = bh & 7;
    int sp   = row & 2047;
    int n    = sp >> 7;
    int i    = sp & 127;
    float qdec = expf(-slopes[h] * (float)i);

    size_t base = (size_t)row * HD;
    float q0 = hdn_in[base + lane];
    float q1 = (lane < 16) ? hdn_in[base + 64 + lane] : 0.f;

    const float* KV = kvs + ((size_t)bh * NC + n) * (HD * HD);
    float a0 = 0.f, a1 = 0.f;
    for (int e = 0; e < HD; ++e) {
        float qe = (e < 64) ? __shfl(q0, e) : __shfl(q1, e - 64);
        a0 += qe * KV[e * HD + lane];
        if (lane < 16) a1 += qe * KV[e * HD + 64 + lane];
    }
    float t0 = oin[base + lane] + qdec * a0 + res[base + lane];
    float t1 = 0.f;
    if (lane < 16) t1 = oin[base + 64 + lane] + qdec * a1 + res[base + 64 + lane];

    float s  = t0 + t1;
    float sq = t0 * t0 + t1 * t1;
#pragma unroll
    for (int o = 32; o; o >>= 1) { s += __shfl_xor(s, o); sq += __shfl_xor(sq, o); }
    float m    = s * (1.f / 80.f);
    float var  = sq * (1.f / 80.f) - m * m;
    float rstd = rsqrtf(var + 1e-5f);
    hdn_out[base + lane] = (t0 - m) * rstd * g[lane] + be[lane];
    if (lane < 16)
        hdn_out[base + 64 + lane] = (t1 - m) * rstd * g[64 + lane] + be[64 + lane];
}

// ---------------------------------------------------------------------------
// Kernel 5: FFN via bf16 MFMA (80 ->pad96-> 480 leaky -> 80) + res + LN.
// One block = 64 rows = 4 waves x 16 rows. Hidden tiled in 5 chunks of 96.
// LDS strides padded to 104 bf16 (208B = 52 banks) -> <=2-way conflicts.
// Hs (hidden, C-layout -> A-layout round trip) aliases the W1 tile buffer.
__global__ __launch_bounds__(256, 3) void k_ffn(const float* __restrict__ hdn_in,
                                                const ushortT* __restrict__ W1T,
                                                const float* __restrict__ b1,
                                                const ushortT* __restrict__ W2T,
                                                const float* __restrict__ b2,
                                                const float* __restrict__ res,
                                                const float* __restrict__ g,
                                                const float* __restrict__ be,
                                                float* __restrict__ hdn_out) {
    __shared__ ushortT Xs[64 * 104];    // X tile, K padded 80->96(->104)
    __shared__ ushortT Ws[96 * 104];    // W1T tile; Hs aliases rows 0..63
    __shared__ ushortT W2s[80 * 104];   // W2T tile
    ushortT* Hs = Ws;

    int t    = threadIdx.x;
    int wave = t >> 6, lane = t & 63;
    int qd   = lane >> 4, ln16 = lane & 15;
    size_t rowbase = (size_t)blockIdx.x * 64;

    // stage X: fp32 -> bf16, zero K-pad 80..95
    for (int u = t; u < 64 * 80; u += 256) {
        int i = u / 80, c = u - i * 80;
        Xs[i * 104 + c] = f2bf(hdn_in[(rowbase + i) * HD + c]);
    }
    for (int u = t; u < 64 * 16; u += 256) {
        int i = u >> 4, c = u & 15;
        Xs[i * 104 + 80 + c] = 0;
    }

    f4 acc[5];
#pragma unroll
    for (int ot = 0; ot < 5; ++ot) acc[ot] = (f4)0.f;

    const uint* W1T32 = (const uint*)W1T;
    const uint* W2T32 = (const uint*)W2T;
    uint* Wsu  = (uint*)Ws;
    uint* W2su = (uint*)W2s;

    for (int jt = 0; jt < DH; jt += 96) {
        // stage W1T tile (96 rows x 96 cols, as 48 uints/row) + W2T tile (80x96)
        for (int u = t; u < 96 * 48; u += 256) {
            int n = u / 48, k2 = u - n * 48;
            Wsu[n * 52 + k2] = W1T32[(size_t)(jt + n) * 48 + k2];
        }
        for (int u = t; u < 80 * 48; u += 256) {
            int n = u / 48, k2 = u - n * 48;
            W2su[n * 52 + k2] = W2T32[(size_t)n * 240 + (jt >> 1) + k2];
        }
        __syncthreads();

        // GEMM1: hidden chunk = X @ W1[:, jt:jt+96]
        bfrag a[3];
#pragma unroll
        for (int ks = 0; ks < 3; ++ks)
            a[ks] = *(const bfrag*)&Xs[(wave * 16 + ln16) * 104 + ks * 32 + qd * 8];
        f4 hc[6];
#pragma unroll
        for (int nt = 0; nt < 6; ++nt) {
            f4 c = (f4)0.f;
#pragma unroll
            for (int ks = 0; ks < 3; ++ks) {
                bfrag b = *(const bfrag*)&Ws[(nt * 16 + ln16) * 104 + ks * 32 + qd * 8];
                c = __builtin_amdgcn_mfma_f32_16x16x32_bf16(a[ks], b, c, 0, 0, 0);
            }
            hc[nt] = c;
        }
        __syncthreads();   // all waves done reading W1 tile

        // leaky-relu + bf16, write hidden to Hs (aliases Ws rows 0..63)
#pragma unroll
        for (int nt = 0; nt < 6; ++nt) {
            float bv = b1[jt + nt * 16 + ln16];
#pragma unroll
            for (int r = 0; r < 4; ++r) {
                float v = hc[nt][r] + bv;
                v = (v > 0.f) ? v : 0.01f * v;
                Hs[(wave * 16 + qd * 4 + r) * 104 + nt * 16 + ln16] = f2bf(v);
            }
        }
        __syncthreads();

        // GEMM2: acc += H_chunk @ W2[jt:jt+96, :]
        bfrag a2[3];
#pragma unroll
        for (int ks = 0; ks < 3; ++ks)
            a2[ks] = *(const bfrag*)&Hs[(wave * 16 + ln16) * 104 + ks * 32 + qd * 8];
#pragma unroll
        for (int ot = 0; ot < 5; ++ot) {
            f4 c = acc[ot];
#pragma unroll
            for (int ks = 0; ks < 3; ++ks) {
                bfrag b = *(const bfrag*)&W2s[(ot * 16 + ln16) * 104 + ks * 32 + qd * 8];
                c = __builtin_amdgcn_mfma_f32_16x16x32_bf16(a2[ks], b, c, 0, 0, 0);
            }
            acc[ot] = c;
        }
        __syncthreads();   // before next chunk's staging overwrites Ws/W2s
    }

    // epilogue: + b2 + residual, LN per row (C-layout: row=qd*4+r, col=ot*16+ln16)
    float tv[5][4];
#pragma unroll
    for (int ot = 0; ot < 5; ++ot) {
        int col = ot * 16 + ln16;
        float b2v = b2[col];
#pragma unroll
        for (int r = 0; r < 4; ++r) {
            size_t row = rowbase + wave * 16 + qd * 4 + r;
            tv[ot][r] = acc[ot][r] + b2v + res[row * HD + col];
        }
    }
#pragma unroll
    for (int r = 0; r < 4; ++r) {
        float s = 0.f, sq = 0.f;
#pragma unroll
        for (int ot = 0; ot < 5; ++ot) { s += tv[ot][r]; sq += tv[ot][r] * tv[ot][r]; }
#pragma unroll
        for (int o = 8; o; o >>= 1) { s += __shfl_xor(s, o); sq += __shfl_xor(sq, o); }
        float m    = s * (1.f / 80.f);
        float var  = sq * (1.f / 80.f) - m * m;
        float rstd = rsqrtf(var + 1e-5f);
        size_t row = rowbase + wave * 16 + qd * 4 + r;
#pragma unroll
        for (int ot = 0; ot < 5; ++ot) {
            int col = ot * 16 + ln16;
            hdn_out[row * HD + col] = (tv[ot][r] - m) * rstd * g[col] + be[col];
        }
    }
}

// ---------------------------------------------------------------------------
// Kernel 6: mean over heads -> (B, S, HD)
__global__ __launch_bounds__(256) void k_mean(const float* __restrict__ hdn,
                                              float* __restrict__ out) {
    int idx = blockIdx.x * 256 + threadIdx.x;
    int b   = idx / (SS * HD);
    int sd  = idx - b * (SS * HD);
    float s = 0.f;
#pragma unroll
    for (int h = 0; h < HH; ++h)
        s += hdn[((size_t)(b * HH + h)) * (SS * HD) + sd];
    out[idx] = s * 0.125f;
}

// ---------------------------------------------------------------------------
extern "C" void kernel_launch(void* const* d_in, const int* in_sizes, int n_in,
                              void* d_out, int out_size, void* d_ws, size_t ws_size,
                              hipStream_t stream) {
    (void)in_sizes; (void)n_in; (void)out_size; (void)ws_size;
    const float* x      = (const float*)d_in[0];
    const float* W1     = (const float*)d_in[1];
    const float* b1     = (const float*)d_in[2];
    const float* W2     = (const float*)d_in[3];
    const float* b2     = (const float*)d_in[4];
    const float* gamma  = (const float*)d_in[5];
    const float* beta   = (const float*)d_in[6];
    const float* slopes = (const float*)d_in[7];
    float* out = (float*)d_out;
    float* ws  = (float*)d_ws;

    float* res = ws;                 // 5,242,880 floats
    float* hdn = ws + ROWSZ;         // 5,242,880
    float* oin = ws + 2 * ROWSZ;     // 5,242,880
    float* kv  = ws + 3 * ROWSZ;     // 32*16*6400 = 3,276,800

    // bf16 transposed weights live in d_out scratch (k_mean overwrites it last)
    ushortT* W1T = (ushortT*)d_out;            // 480*96
    ushortT* W2T = W1T + 480 * 96;             // 80*480

    k_prep<<<(480 * 96 + 80 * 480 + 255) / 256, 256, 0, stream>>>(W1, W2, W1T, W2T);
    k_ln0<<<NROW / 4, 256, 0, stream>>>(x, gamma, beta, hdn, res);
    for (int it = 0; it < 2; ++it) {
        k_attn_a<<<BB * HH * NC, 256, 0, stream>>>(hdn, slopes, oin, kv);
        k_scan<<<(BB * HH * HD * HD) / 256, 256, 0, stream>>>(kv, slopes);
        k_attn_b<<<NROW / 4, 256, 0, stream>>>(hdn, oin, kv, res, slopes, gamma, beta, hdn);
        k_ffn<<<NROW / 64, 256, 0, stream>>>(hdn, W1T, b1, W2T, b2, res, gamma, beta, hdn);
    }
    k_mean<<<(BB * SS * HD) / 256, 256, 0, stream>>>(hdn, out);
}

// Round 3
// 480.183 us; speedup vs baseline: 2.5070x; 1.8664x over previous
//
#include <hip/hip_runtime.h>
#include <hip/hip_bf16.h>

// Problem constants
#define BB 4
#define HH 8
#define SS 2048
#define HD 80
#define CC 128
#define NC 16
#define DH 480           // MULT*HD
#define NROW (BB*HH*SS)  // 65536
#define ROWSZ ((size_t)NROW * HD)  // 5,242,880 floats per tensor buffer

typedef unsigned short ushortT;
typedef __attribute__((ext_vector_type(8))) short bfrag;   // 8 bf16 = 4 VGPRs
typedef __attribute__((ext_vector_type(4))) float f4;

__device__ __forceinline__ ushortT f2bf(float f) {
    __hip_bfloat16 h = __float2bfloat16(f);   // RNE
    ushortT u; __builtin_memcpy(&u, &h, 2); return u;
}

// ---------------------------------------------------------------------------
// Kernel 0: prep — transpose + bf16-cast W1 (-> W1T[480][96], K zero-padded)
// and W2 (-> W2T[80][480]). Outputs live in d_out tail (k_mean overwrites last).
__global__ __launch_bounds__(256) void k_prep(const float* __restrict__ W1,
                                              const float* __restrict__ W2,
                                              ushortT* __restrict__ W1T,
                                              ushortT* __restrict__ W2T) {
    int idx = blockIdx.x * 256 + threadIdx.x;
    if (idx < 480 * 96) {
        int n = idx / 96, k = idx - n * 96;
        float v = (k < HD) ? W1[k * DH + n] : 0.f;
        W1T[idx] = f2bf(v);
    } else if (idx < 480 * 96 + 80 * 480) {
        int j = idx - 480 * 96;
        int n = j / DH, k = j - n * DH;
        W2T[j] = f2bf(W2[k * HD + n]);
    }
}

// ---------------------------------------------------------------------------
// Kernel 1: first LN (x reshaped is a pure reinterpret: row = (b*8+h)*2048+s)
__global__ __launch_bounds__(256) void k_ln0(const float* __restrict__ x,
                                             const float* __restrict__ g,
                                             const float* __restrict__ be,
                                             float* __restrict__ hdn,
                                             float* __restrict__ res) {
    int row  = blockIdx.x * 4 + (threadIdx.x >> 6);
    int lane = threadIdx.x & 63;
    const float* xr = x + (size_t)row * HD;
    float v0 = xr[lane];
    float v1 = (lane < 16) ? xr[64 + lane] : 0.f;
    float s  = v0 + v1;
    float sq = v0 * v0 + v1 * v1;
#pragma unroll
    for (int o = 32; o; o >>= 1) { s += __shfl_xor(s, o); sq += __shfl_xor(sq, o); }
    float m    = s * (1.f / 80.f);
    float var  = sq * (1.f / 80.f) - m * m;
    float rstd = rsqrtf(var + 1e-5f);
    size_t base = (size_t)row * HD;
    float y0 = (v0 - m) * rstd * g[lane] + be[lane];
    hdn[base + lane] = y0; res[base + lane] = y0;
    if (lane < 16) {
        float y1 = (v1 - m) * rstd * g[64 + lane] + be[64 + lane];
        hdn[base + 64 + lane] = y1; res[base + 64 + lane] = y1;
    }
}

// ---------------------------------------------------------------------------
// Kernel 2: per-chunk intra attention + chunk KV outer product (fp32).
__global__ __launch_bounds__(256) void k_attn_a(const float* __restrict__ hdn,
                                                const float* __restrict__ slopes,
                                                float* __restrict__ oin,
                                                float* __restrict__ ckv) {
    __shared__ float X[CC][HD + 1];
    __shared__ float SC[CC][33];
    __shared__ float qd[CC], ek[CC], kd[CC];

    int t  = threadIdx.x;
    int bk = blockIdx.x;
    int bh = bk >> 4;
    int n  = bk & 15;
    int h  = bh & 7;
    float sl = slopes[h];

    const float* xb = hdn + ((size_t)bh * SS + (size_t)n * CC) * HD;
    for (int u = t; u < CC * HD; u += 256) {
        int i = u / HD, k = u - i * HD;
        X[i][k] = xb[u];
    }
    if (t < CC) {
        qd[t] = expf(-sl * (float)t);
        ek[t] = expf( sl * (float)t);
        kd[t] = expf(-sl * (float)(CC - t));
    }
    __syncthreads();

    int i_o   = t >> 1;
    int dbase = (t & 1) * 40;
    float oacc[40];
#pragma unroll
    for (int m = 0; m < 40; ++m) oacc[m] = 0.f;

    int ig = t >> 3;
    int jg = t & 7;

    for (int jt = 0; jt < 4; ++jt) {
        int j0 = jt * 32;
        float acc[4][4];
#pragma unroll
        for (int a = 0; a < 4; ++a)
#pragma unroll
            for (int b = 0; b < 4; ++b) acc[a][b] = 0.f;
        for (int k = 0; k < HD; ++k) {
            float xa[4], xv[4];
#pragma unroll
            for (int a = 0; a < 4; ++a) xa[a] = X[ig * 4 + a][k];
#pragma unroll
            for (int b = 0; b < 4; ++b) xv[b] = X[j0 + jg * 4 + b][k];
#pragma unroll
            for (int a = 0; a < 4; ++a)
#pragma unroll
                for (int b = 0; b < 4; ++b) acc[a][b] += xa[a] * xv[b];
        }
#pragma unroll
        for (int a = 0; a < 4; ++a)
#pragma unroll
            for (int b = 0; b < 4; ++b) {
                int i = ig * 4 + a, j = j0 + jg * 4 + b;
                float f = (i >= j) ? qd[i] * ek[j] : 0.f;
                SC[i][jg * 4 + b] = acc[a][b] * f;
            }
        __syncthreads();
        for (int jj = 0; jj < 32; ++jj) {
            float scv = SC[i_o][jj];
            const float* xrow = &X[j0 + jj][dbase];
#pragma unroll
            for (int m = 0; m < 40; ++m) oacc[m] += scv * xrow[m];
        }
        __syncthreads();
    }
    float* orow = oin + ((size_t)bh * SS + (size_t)n * CC + i_o) * HD + dbase;
#pragma unroll
    for (int m = 0; m < 40; ++m) orow[m] = oacc[m];

    int eg = t >> 4;
    int dg = t & 15;
    float ka[5][5];
#pragma unroll
    for (int a = 0; a < 5; ++a)
#pragma unroll
        for (int b = 0; b < 5; ++b) ka[a][b] = 0.f;
    for (int j = 0; j < CC; ++j) {
        float kdj = kd[j];
        float xe[5], xd[5];
#pragma unroll
        for (int a = 0; a < 5; ++a) xe[a] = X[j][eg * 5 + a] * kdj;
#pragma unroll
        for (int b = 0; b < 5; ++b) xd[b] = X[j][dg * 5 + b];
#pragma unroll
        for (int a = 0; a < 5; ++a)
#pragma unroll
            for (int b = 0; b < 5; ++b) ka[a][b] += xe[a] * xd[b];
    }
    float* kvout = ckv + (size_t)bk * (HD * HD);
#pragma unroll
    for (int a = 0; a < 5; ++a)
#pragma unroll
        for (int b = 0; b < 5; ++b)
            kvout[(eg * 5 + a) * HD + dg * 5 + b] = ka[a][b];
}

// ---------------------------------------------------------------------------
// Kernel 3: in-place decay prefix-scan over chunk KVs.
__global__ __launch_bounds__(256) void k_scan(float* __restrict__ kv,
                                              const float* __restrict__ slopes) {
    int idx = blockIdx.x * 256 + threadIdx.x;
    int bh  = idx / (HD * HD);
    int ed  = idx - bh * (HD * HD);
    float bd = expf(-slopes[bh & 7] * (float)CC);
    size_t base = (size_t)bh * NC * (HD * HD) + ed;
    float st = 0.f;
#pragma unroll
    for (int n = 0; n < NC; ++n) {
        size_t p = base + (size_t)n * (HD * HD);
        float cv = kv[p];
        kv[p] = st;
        st = bd * st + cv;
    }
}

// ---------------------------------------------------------------------------
// Kernel 4: inter-chunk term via bf16 MFMA, fused + intra + residual + LN.
// One block per chunk (bh, n): [128x80] q @ [80x80] KV-state, 4 waves.
// A-layout: q rows contiguous in k. B-layout needs k contiguous per col ->
// stage KV TRANSPOSED (KVT[d][e]). K padded 80->96; strides 104 (odd*8B).
__global__ __launch_bounds__(256) void k_attn_b(const float* __restrict__ hdn_in,
                                                const float* __restrict__ oin,
                                                const float* __restrict__ kvs,
                                                const float* __restrict__ res,
                                                const float* __restrict__ slopes,
                                                const float* __restrict__ g,
                                                const float* __restrict__ be,
                                                float* __restrict__ hdn_out) {
    __shared__ ushortT Qs[CC * 104];     // 128 rows x (96 k, padded stride 104)
    __shared__ ushortT KVT[80 * 104];    // 80 d-rows x (96 e, padded stride 104)

    int t    = threadIdx.x;
    int wave = t >> 6, lane = t & 63;
    int qd   = lane >> 4, ln16 = lane & 15;
    int bk = blockIdx.x;
    int bh = bk >> 4;
    int n  = bk & 15;
    float sl = slopes[bh & 7];

    size_t chunkrow = (size_t)bh * SS + (size_t)n * CC;   // first global row
    const float* xb = hdn_in + chunkrow * HD;
    const float* KV = kvs + ((size_t)bh * NC + n) * (HD * HD);

    // stage q chunk (bf16, zero K-pad 80..95)
    for (int u = t; u < CC * HD; u += 256) {
        int i = u / HD, c = u - i * HD;
        Qs[i * 104 + c] = f2bf(xb[u]);
    }
    for (int u = t; u < CC * 16; u += 256) {
        int i = u >> 4, c = u & 15;
        Qs[i * 104 + 80 + c] = 0;
    }
    // stage KV transposed (bf16, zero e-pad 80..95)
    for (int u = t; u < HD * HD; u += 256) {
        int e = u / HD, d = u - e * HD;
        KVT[d * 104 + e] = f2bf(KV[u]);
    }
    for (int u = t; u < HD * 16; u += 256) {
        int d = u >> 4, e = u & 15;
        KVT[d * 104 + 80 + e] = 0;
    }
    __syncthreads();

    // each wave: rows [wave*32, wave*32+32) = 2 row-tiles; 5 col-tiles; K=96
    int m0 = wave * 32;
    bfrag a[2][3];
#pragma unroll
    for (int rt = 0; rt < 2; ++rt)
#pragma unroll
        for (int ks = 0; ks < 3; ++ks)
            a[rt][ks] = *(const bfrag*)&Qs[(m0 + rt * 16 + ln16) * 104 + ks * 32 + qd * 8];

    f4 acc[2][5];
#pragma unroll
    for (int ot = 0; ot < 5; ++ot) {
#pragma unroll
        for (int rt = 0; rt < 2; ++rt) acc[rt][ot] = (f4)0.f;
#pragma unroll
        for (int ks = 0; ks < 3; ++ks) {
            bfrag b = *(const bfrag*)&KVT[(ot * 16 + ln16) * 104 + ks * 32 + qd * 8];
#pragma unroll
            for (int rt = 0; rt < 2; ++rt)
                acc[rt][ot] = __builtin_amdgcn_mfma_f32_16x16x32_bf16(a[rt][ks], b, acc[rt][ot], 0, 0, 0);
        }
    }

    // epilogue: o = oin + qdec(i)*acc + res, then LN. C-layout: col = ot*16+ln16,
    // row-in-tile = qd*4 + r.
#pragma unroll
    for (int rt = 0; rt < 2; ++rt) {
#pragma unroll
        for (int r = 0; r < 4; ++r) {
            int i = m0 + rt * 16 + qd * 4 + r;         // row within chunk
            float qdec = expf(-sl * (float)i);
            size_t grow = (chunkrow + i) * HD;
            float tv[5];
            float s = 0.f, sq = 0.f;
#pragma unroll
            for (int ot = 0; ot < 5; ++ot) {
                int col = ot * 16 + ln16;
                tv[ot] = oin[grow + col] + qdec * acc[rt][ot][r] + res[grow + col];
                s += tv[ot]; sq += tv[ot] * tv[ot];
            }
#pragma unroll
            for (int o = 8; o; o >>= 1) { s += __shfl_xor(s, o); sq += __shfl_xor(sq, o); }
            float m    = s * (1.f / 80.f);
            float var  = sq * (1.f / 80.f) - m * m;
            float rstd = rsqrtf(var + 1e-5f);
#pragma unroll
            for (int ot = 0; ot < 5; ++ot) {
                int col = ot * 16 + ln16;
                hdn_out[grow + col] = (tv[ot] - m) * rstd * g[col] + be[col];
            }
        }
    }
}

// ---------------------------------------------------------------------------
// Kernel 5: FFN via bf16 MFMA (80 ->pad96-> 480 leaky -> 80) + res + LN.
__global__ __launch_bounds__(256, 3) void k_ffn(const float* __restrict__ hdn_in,
                                                const ushortT* __restrict__ W1T,
                                                const float* __restrict__ b1,
                                                const ushortT* __restrict__ W2T,
                                                const float* __restrict__ b2,
                                                const float* __restrict__ res,
                                                const float* __restrict__ g,
                                                const float* __restrict__ be,
                                                float* __restrict__ hdn_out) {
    __shared__ ushortT Xs[64 * 104];    // X tile, K padded 80->96(->104)
    __shared__ ushortT Ws[96 * 104];    // W1T tile; Hs aliases rows 0..63
    __shared__ ushortT W2s[80 * 104];   // W2T tile
    ushortT* Hs = Ws;

    int t    = threadIdx.x;
    int wave = t >> 6, lane = t & 63;
    int qd   = lane >> 4, ln16 = lane & 15;
    size_t rowbase = (size_t)blockIdx.x * 64;

    for (int u = t; u < 64 * 80; u += 256) {
        int i = u / 80, c = u - i * 80;
        Xs[i * 104 + c] = f2bf(hdn_in[(rowbase + i) * HD + c]);
    }
    for (int u = t; u < 64 * 16; u += 256) {
        int i = u >> 4, c = u & 15;
        Xs[i * 104 + 80 + c] = 0;
    }

    f4 acc[5];
#pragma unroll
    for (int ot = 0; ot < 5; ++ot) acc[ot] = (f4)0.f;

    const uint* W1T32 = (const uint*)W1T;
    const uint* W2T32 = (const uint*)W2T;
    uint* Wsu  = (uint*)Ws;
    uint* W2su = (uint*)W2s;

    for (int jt = 0; jt < DH; jt += 96) {
        for (int u = t; u < 96 * 48; u += 256) {
            int n = u / 48, k2 = u - n * 48;
            Wsu[n * 52 + k2] = W1T32[(size_t)(jt + n) * 48 + k2];
        }
        for (int u = t; u < 80 * 48; u += 256) {
            int n = u / 48, k2 = u - n * 48;
            W2su[n * 52 + k2] = W2T32[(size_t)n * 240 + (jt >> 1) + k2];
        }
        __syncthreads();

        bfrag a[3];
#pragma unroll
        for (int ks = 0; ks < 3; ++ks)
            a[ks] = *(const bfrag*)&Xs[(wave * 16 + ln16) * 104 + ks * 32 + qd * 8];
        f4 hc[6];
#pragma unroll
        for (int nt = 0; nt < 6; ++nt) {
            f4 c = (f4)0.f;
#pragma unroll
            for (int ks = 0; ks < 3; ++ks) {
                bfrag b = *(const bfrag*)&Ws[(nt * 16 + ln16) * 104 + ks * 32 + qd * 8];
                c = __builtin_amdgcn_mfma_f32_16x16x32_bf16(a[ks], b, c, 0, 0, 0);
            }
            hc[nt] = c;
        }
        __syncthreads();

#pragma unroll
        for (int nt = 0; nt < 6; ++nt) {
            float bv = b1[jt + nt * 16 + ln16];
#pragma unroll
            for (int r = 0; r < 4; ++r) {
                float v = hc[nt][r] + bv;
                v = (v > 0.f) ? v : 0.01f * v;
                Hs[(wave * 16 + qd * 4 + r) * 104 + nt * 16 + ln16] = f2bf(v);
            }
        }
        __syncthreads();

        bfrag a2[3];
#pragma unroll
        for (int ks = 0; ks < 3; ++ks)
            a2[ks] = *(const bfrag*)&Hs[(wave * 16 + ln16) * 104 + ks * 32 + qd * 8];
#pragma unroll
        for (int ot = 0; ot < 5; ++ot) {
            f4 c = acc[ot];
#pragma unroll
            for (int ks = 0; ks < 3; ++ks) {
                bfrag b = *(const bfrag*)&W2s[(ot * 16 + ln16) * 104 + ks * 32 + qd * 8];
                c = __builtin_amdgcn_mfma_f32_16x16x32_bf16(a2[ks], b, c, 0, 0, 0);
            }
            acc[ot] = c;
        }
        __syncthreads();
    }

    float tv[5][4];
#pragma unroll
    for (int ot = 0; ot < 5; ++ot) {
        int col = ot * 16 + ln16;
        float b2v = b2[col];
#pragma unroll
        for (int r = 0; r < 4; ++r) {
            size_t row = rowbase + wave * 16 + qd * 4 + r;
            tv[ot][r] = acc[ot][r] + b2v + res[row * HD + col];
        }
    }
#pragma unroll
    for (int r = 0; r < 4; ++r) {
        float s = 0.f, sq = 0.f;
#pragma unroll
        for (int ot = 0; ot < 5; ++ot) { s += tv[ot][r]; sq += tv[ot][r] * tv[ot][r]; }
#pragma unroll
        for (int o = 8; o; o >>= 1) { s += __shfl_xor(s, o); sq += __shfl_xor(sq, o); }
        float m    = s * (1.f / 80.f);
        float var  = sq * (1.f / 80.f) - m * m;
        float rstd = rsqrtf(var + 1e-5f);
        size_t row = rowbase + wave * 16 + qd * 4 + r;
#pragma unroll
        for (int ot = 0; ot < 5; ++ot) {
            int col = ot * 16 + ln16;
            hdn_out[row * HD + col] = (tv[ot][r] - m) * rstd * g[col] + be[col];
        }
    }
}

// ---------------------------------------------------------------------------
// Kernel 6: mean over heads -> (B, S, HD)
__global__ __launch_bounds__(256) void k_mean(const float* __restrict__ hdn,
                                              float* __restrict__ out) {
    int idx = blockIdx.x * 256 + threadIdx.x;
    int b   = idx / (SS * HD);
    int sd  = idx - b * (SS * HD);
    float s = 0.f;
#pragma unroll
    for (int h = 0; h < HH; ++h)
        s += hdn[((size_t)(b * HH + h)) * (SS * HD) + sd];
    out[idx] = s * 0.125f;
}

// ---------------------------------------------------------------------------
extern "C" void kernel_launch(void* const* d_in, const int* in_sizes, int n_in,
                              void* d_out, int out_size, void* d_ws, size_t ws_size,
                              hipStream_t stream) {
    (void)in_sizes; (void)n_in; (void)out_size; (void)ws_size;
    const float* x      = (const float*)d_in[0];
    const float* W1     = (const float*)d_in[1];
    const float* b1     = (const float*)d_in[2];
    const float* W2     = (const float*)d_in[3];
    const float* b2     = (const float*)d_in[4];
    const float* gamma  = (const float*)d_in[5];
    const float* beta   = (const float*)d_in[6];
    const float* slopes = (const float*)d_in[7];
    float* out = (float*)d_out;
    float* ws  = (float*)d_ws;

    float* res = ws;                 // 5,242,880 floats
    float* hdn = ws + ROWSZ;         // 5,242,880
    float* oin = ws + 2 * ROWSZ;     // 5,242,880
    float* kv  = ws + 3 * ROWSZ;     // 32*16*6400 = 3,276,800

    // bf16 transposed weights live in d_out scratch (k_mean overwrites it last)
    ushortT* W1T = (ushortT*)d_out;            // 480*96
    ushortT* W2T = W1T + 480 * 96;             // 80*480

    k_prep<<<(480 * 96 + 80 * 480 + 255) / 256, 256, 0, stream>>>(W1, W2, W1T, W2T);
    k_ln0<<<NROW / 4, 256, 0, stream>>>(x, gamma, beta, hdn, res);
    for (int it = 0; it < 2; ++it) {
        k_attn_a<<<BB * HH * NC, 256, 0, stream>>>(hdn, slopes, oin, kv);
        k_scan<<<(BB * HH * HD * HD) / 256, 256, 0, stream>>>(kv, slopes);
        k_attn_b<<<BB * HH * NC, 256, 0, stream>>>(hdn, oin, kv, res, slopes, gamma, beta, hdn);
        k_ffn<<<NROW / 64, 256, 0, stream>>>(hdn, W1T, b1, W2T, b2, res, gamma, beta, hdn);
    }
    k_mean<<<(BB * SS * HD) / 256, 256, 0, stream>>>(hdn, out);
}

// Round 4
// 331.589 us; speedup vs baseline: 3.6304x; 1.4481x over previous
//
#include <hip/hip_runtime.h>
#include <hip/hip_bf16.h>

// Problem constants
#define BB 4
#define HH 8
#define SS 2048
#define HD 80
#define CC 128
#define NC 16
#define DH 480           // MULT*HD
#define NROW (BB*HH*SS)  // 65536
#define ROWSZ ((size_t)NROW * HD)  // 5,242,880 floats per tensor buffer

typedef unsigned short ushortT;
typedef __attribute__((ext_vector_type(8))) short bfrag;   // 8 bf16 = 4 VGPRs
typedef __attribute__((ext_vector_type(4))) float f4;

__device__ __forceinline__ ushortT f2bf(float f) {
    __hip_bfloat16 h = __float2bfloat16(f);   // RNE
    ushortT u; __builtin_memcpy(&u, &h, 2); return u;
}
__device__ __forceinline__ float bf2f(ushortT u) {
    unsigned int x = ((unsigned int)u) << 16;
    float f; __builtin_memcpy(&f, &x, 4); return f;
}

// ---------------------------------------------------------------------------
// Kernel 0: prep — transpose + bf16-cast W1 (-> W1T[480][96], K zero-padded)
// and W2 (-> W2T[80][480]). Outputs live in d_out tail (k_mean overwrites last).
__global__ __launch_bounds__(256) void k_prep(const float* __restrict__ W1,
                                              const float* __restrict__ W2,
                                              ushortT* __restrict__ W1T,
                                              ushortT* __restrict__ W2T) {
    int idx = blockIdx.x * 256 + threadIdx.x;
    if (idx < 480 * 96) {
        int n = idx / 96, k = idx - n * 96;
        float v = (k < HD) ? W1[k * DH + n] : 0.f;
        W1T[idx] = f2bf(v);
    } else if (idx < 480 * 96 + 80 * 480) {
        int j = idx - 480 * 96;
        int n = j / DH, k = j - n * DH;
        W2T[j] = f2bf(W2[k * HD + n]);
    }
}

// ---------------------------------------------------------------------------
// Kernel 1: first LN (x reshaped is a pure reinterpret: row = (b*8+h)*2048+s)
__global__ __launch_bounds__(256) void k_ln0(const float* __restrict__ x,
                                             const float* __restrict__ g,
                                             const float* __restrict__ be,
                                             float* __restrict__ hdn,
                                             float* __restrict__ res) {
    int row  = blockIdx.x * 4 + (threadIdx.x >> 6);
    int lane = threadIdx.x & 63;
    const float* xr = x + (size_t)row * HD;
    float v0 = xr[lane];
    float v1 = (lane < 16) ? xr[64 + lane] : 0.f;
    float s  = v0 + v1;
    float sq = v0 * v0 + v1 * v1;
#pragma unroll
    for (int o = 32; o; o >>= 1) { s += __shfl_xor(s, o); sq += __shfl_xor(sq, o); }
    float m    = s * (1.f / 80.f);
    float var  = sq * (1.f / 80.f) - m * m;
    float rstd = rsqrtf(var + 1e-5f);
    size_t base = (size_t)row * HD;
    float y0 = (v0 - m) * rstd * g[lane] + be[lane];
    hdn[base + lane] = y0; res[base + lane] = y0;
    if (lane < 16) {
        float y1 = (v1 - m) * rstd * g[64 + lane] + be[64 + lane];
        hdn[base + 64 + lane] = y1; res[base + 64 + lane] = y1;
    }
}

// ---------------------------------------------------------------------------
// Kernel 2: per-chunk intra attention + chunk KV, all via bf16 MFMA.
// One block per (bh, chunk). 4 waves; m-tiles interleaved (wave owns {w,w+4})
// for causal load balance. Main loop is barrier-free: SC rows are wave-private
// and same-wave ds ordering is lgkmcnt-enforced.
// KV = sum_j kd[j] X[j]^T X[j] is a symmetric Gram form: fold sqrt(kd) into
// XT in-place (one barrier pair), then A and B both read XT.
__global__ __launch_bounds__(256) void k_attn_a(const float* __restrict__ hdn,
                                                const float* __restrict__ slopes,
                                                float* __restrict__ oin,
                                                float* __restrict__ ckv) {
    __shared__ ushortT Xs[CC * 104];   // 128 rows x 96(k-pad, stride 104)
    __shared__ ushortT SC[CC * 40];    // 128 rows x 32(pad 40) score block, A-layout
    __shared__ ushortT XT[HD * 136];   // 80 d-rows x 128 j (stride 136)
    __shared__ float dec[CC];          // exp(-sl*delta)
    __shared__ float sqk[CC];          // sqrt(kd[j]) = exp(-0.5*sl*(128-j))

    int t    = threadIdx.x;
    int wave = t >> 6, lane = t & 63;
    int quad = lane >> 4, ln16 = lane & 15;
    int bk = blockIdx.x;
    int bh = bk >> 4;
    int n  = bk & 15;
    float sl = slopes[bh & 7];

    size_t chunkrow = (size_t)bh * SS + (size_t)n * CC;
    const float* xb = hdn + chunkrow * HD;

    if (t < CC) {
        dec[t] = expf(-sl * (float)t);
        sqk[t] = expf(-0.5f * sl * (float)(CC - t));
    }
    // stage Xs (row-major) + XT (transposed) in one pass
    for (int u = t; u < CC * HD; u += 256) {
        int i = u / HD, c = u - i * HD;
        ushortT v = f2bf(xb[u]);
        Xs[i * 104 + c] = v;
        XT[c * 136 + i] = v;
    }
    for (int u = t; u < CC * 16; u += 256) {
        int i = u >> 4, c = u & 15;
        Xs[i * 104 + 80 + c] = 0;
    }
    __syncthreads();

    // preload A-frags for this wave's two m-tiles (rows mt*16 + ln16)
    bfrag a[2][3];
#pragma unroll
    for (int rt = 0; rt < 2; ++rt) {
        int mt = wave + rt * 4;
#pragma unroll
        for (int ks = 0; ks < 3; ++ks)
            a[rt][ks] = *(const bfrag*)&Xs[(mt * 16 + ln16) * 104 + ks * 32 + quad * 8];
    }

    f4 oacc[2][5];
#pragma unroll
    for (int rt = 0; rt < 2; ++rt)
#pragma unroll
        for (int ot = 0; ot < 5; ++ot) oacc[rt][ot] = (f4)0.f;

    for (int jt = 0; jt < 4; ++jt) {
        if (wave + 4 < 2 * jt) continue;   // both m-tiles fully masked
        int j0 = jt * 32;
        bfrag bq[2][3];
#pragma unroll
        for (int nt = 0; nt < 2; ++nt)
#pragma unroll
            for (int ks = 0; ks < 3; ++ks)
                bq[nt][ks] = *(const bfrag*)&Xs[(j0 + nt * 16 + ln16) * 104 + ks * 32 + quad * 8];

#pragma unroll
        for (int rt = 0; rt < 2; ++rt) {
            int mt = wave + rt * 4;
            if (mt < 2 * jt) continue;     // this m-tile fully above diagonal
            int i_base = mt * 16;
            // MFMA1: S block [16 x 32] over K=96
            f4 c0 = (f4)0.f, c1 = (f4)0.f;
#pragma unroll
            for (int ks = 0; ks < 3; ++ks) {
                c0 = __builtin_amdgcn_mfma_f32_16x16x32_bf16(a[rt][ks], bq[0][ks], c0, 0, 0, 0);
                c1 = __builtin_amdgcn_mfma_f32_16x16x32_bf16(a[rt][ks], bq[1][ks], c1, 0, 0, 0);
            }
            // decay-mask (fp32) + write SC (A-layout, wave-private rows)
#pragma unroll
            for (int r = 0; r < 4; ++r) {
                int i = i_base + quad * 4 + r;
                int d0 = i - (j0 + ln16);
                int d1 = d0 - 16;
                float f0 = (d0 >= 0) ? dec[d0] : 0.f;
                float f1 = (d1 >= 0) ? dec[d1] : 0.f;
                SC[i * 40 + ln16]      = f2bf(c0[r] * f0);
                SC[i * 40 + 16 + ln16] = f2bf(c1[r] * f1);
            }
            // MFMA2: O += S_block @ V_block  (A from SC, B from XT)
            bfrag a2 = *(const bfrag*)&SC[(i_base + ln16) * 40 + quad * 8];
#pragma unroll
            for (int ot = 0; ot < 5; ++ot) {
                bfrag bv = *(const bfrag*)&XT[(ot * 16 + ln16) * 136 + j0 + quad * 8];
                oacc[rt][ot] = __builtin_amdgcn_mfma_f32_16x16x32_bf16(a2, bv, oacc[rt][ot], 0, 0, 0);
            }
        }
    }

    // write intra-chunk O (fp32). C-layout: row = quad*4+r, col = ot*16+ln16
#pragma unroll
    for (int rt = 0; rt < 2; ++rt) {
        int i_base = (wave + rt * 4) * 16;
#pragma unroll
        for (int r = 0; r < 4; ++r) {
            size_t grow = (chunkrow + i_base + quad * 4 + r) * HD;
#pragma unroll
            for (int ot = 0; ot < 5; ++ot)
                oin[grow + ot * 16 + ln16] = oacc[rt][ot][r];
        }
    }

    __syncthreads();   // all phase-2 XT reads done
    // in-place scale XT by sqrt(kd[j]): XT becomes Y^T, KV = Gram(Y^T)
    for (int u = t; u < HD * CC; u += 256) {
        int e = u >> 7, j = u & 127;
        int idx = e * 136 + j;
        XT[idx] = f2bf(bf2f(XT[idx]) * sqk[j]);
    }
    __syncthreads();

    // phase 3: KV[e][d] tiles (5x5 of 16x16), strided across waves
    float* kvout = ckv + (size_t)bk * (HD * HD);
    for (int p = wave; p < 25; p += 4) {
        int me = p / 5, ne = p - me * 5;
        f4 c = (f4)0.f;
#pragma unroll
        for (int ks = 0; ks < 4; ++ks) {
            bfrag av = *(const bfrag*)&XT[(me * 16 + ln16) * 136 + ks * 32 + quad * 8];
            bfrag bv = *(const bfrag*)&XT[(ne * 16 + ln16) * 136 + ks * 32 + quad * 8];
            c = __builtin_amdgcn_mfma_f32_16x16x32_bf16(av, bv, c, 0, 0, 0);
        }
#pragma unroll
        for (int r = 0; r < 4; ++r)
            kvout[(me * 16 + quad * 4 + r) * HD + ne * 16 + ln16] = c[r];
    }
}

// ---------------------------------------------------------------------------
// Kernel 3: in-place decay prefix-scan over chunk KVs.
__global__ __launch_bounds__(256) void k_scan(float* __restrict__ kv,
                                              const float* __restrict__ slopes) {
    int idx = blockIdx.x * 256 + threadIdx.x;
    int bh  = idx / (HD * HD);
    int ed  = idx - bh * (HD * HD);
    float bd = expf(-slopes[bh & 7] * (float)CC);
    size_t base = (size_t)bh * NC * (HD * HD) + ed;
    float st = 0.f;
#pragma unroll
    for (int n = 0; n < NC; ++n) {
        size_t p = base + (size_t)n * (HD * HD);
        float cv = kv[p];
        kv[p] = st;
        st = bd * st + cv;
    }
}

// ---------------------------------------------------------------------------
// Kernel 4: inter-chunk term via bf16 MFMA, fused + intra + residual + LN.
__global__ __launch_bounds__(256) void k_attn_b(const float* __restrict__ hdn_in,
                                                const float* __restrict__ oin,
                                                const float* __restrict__ kvs,
                                                const float* __restrict__ res,
                                                const float* __restrict__ slopes,
                                                const float* __restrict__ g,
                                                const float* __restrict__ be,
                                                float* __restrict__ hdn_out) {
    __shared__ ushortT Qs[CC * 104];     // 128 rows x (96 k, padded stride 104)
    __shared__ ushortT KVT[80 * 104];    // 80 d-rows x (96 e, padded stride 104)

    int t    = threadIdx.x;
    int wave = t >> 6, lane = t & 63;
    int qd   = lane >> 4, ln16 = lane & 15;
    int bk = blockIdx.x;
    int bh = bk >> 4;
    int n  = bk & 15;
    float sl = slopes[bh & 7];

    size_t chunkrow = (size_t)bh * SS + (size_t)n * CC;
    const float* xb = hdn_in + chunkrow * HD;
    const float* KV = kvs + ((size_t)bh * NC + n) * (HD * HD);

    for (int u = t; u < CC * HD; u += 256) {
        int i = u / HD, c = u - i * HD;
        Qs[i * 104 + c] = f2bf(xb[u]);
    }
    for (int u = t; u < CC * 16; u += 256) {
        int i = u >> 4, c = u & 15;
        Qs[i * 104 + 80 + c] = 0;
    }
    for (int u = t; u < HD * HD; u += 256) {
        int e = u / HD, d = u - e * HD;
        KVT[d * 104 + e] = f2bf(KV[u]);
    }
    for (int u = t; u < HD * 16; u += 256) {
        int d = u >> 4, e = u & 15;
        KVT[d * 104 + 80 + e] = 0;
    }
    __syncthreads();

    int m0 = wave * 32;
    bfrag a[2][3];
#pragma unroll
    for (int rt = 0; rt < 2; ++rt)
#pragma unroll
        for (int ks = 0; ks < 3; ++ks)
            a[rt][ks] = *(const bfrag*)&Qs[(m0 + rt * 16 + ln16) * 104 + ks * 32 + qd * 8];

    f4 acc[2][5];
#pragma unroll
    for (int ot = 0; ot < 5; ++ot) {
#pragma unroll
        for (int rt = 0; rt < 2; ++rt) acc[rt][ot] = (f4)0.f;
#pragma unroll
        for (int ks = 0; ks < 3; ++ks) {
            bfrag b = *(const bfrag*)&KVT[(ot * 16 + ln16) * 104 + ks * 32 + qd * 8];
#pragma unroll
            for (int rt = 0; rt < 2; ++rt)
                acc[rt][ot] = __builtin_amdgcn_mfma_f32_16x16x32_bf16(a[rt][ks], b, acc[rt][ot], 0, 0, 0);
        }
    }

#pragma unroll
    for (int rt = 0; rt < 2; ++rt) {
#pragma unroll
        for (int r = 0; r < 4; ++r) {
            int i = m0 + rt * 16 + qd * 4 + r;
            float qdec = expf(-sl * (float)i);
            size_t grow = (chunkrow + i) * HD;
            float tv[5];
            float s = 0.f, sq = 0.f;
#pragma unroll
            for (int ot = 0; ot < 5; ++ot) {
                int col = ot * 16 + ln16;
                tv[ot] = oin[grow + col] + qdec * acc[rt][ot][r] + res[grow + col];
                s += tv[ot]; sq += tv[ot] * tv[ot];
            }
#pragma unroll
            for (int o = 8; o; o >>= 1) { s += __shfl_xor(s, o); sq += __shfl_xor(sq, o); }
            float m    = s * (1.f / 80.f);
            float var  = sq * (1.f / 80.f) - m * m;
            float rstd = rsqrtf(var + 1e-5f);
#pragma unroll
            for (int ot = 0; ot < 5; ++ot) {
                int col = ot * 16 + ln16;
                hdn_out[grow + col] = (tv[ot] - m) * rstd * g[col] + be[col];
            }
        }
    }
}

// ---------------------------------------------------------------------------
// Kernel 5: FFN via bf16 MFMA (80 ->pad96-> 480 leaky -> 80) + res + LN.
__global__ __launch_bounds__(256, 3) void k_ffn(const float* __restrict__ hdn_in,
                                                const ushortT* __restrict__ W1T,
                                                const float* __restrict__ b1,
                                                const ushortT* __restrict__ W2T,
                                                const float* __restrict__ b2,
                                                const float* __restrict__ res,
                                                const float* __restrict__ g,
                                                const float* __restrict__ be,
                                                float* __restrict__ hdn_out) {
    __shared__ ushortT Xs[64 * 104];    // X tile, K padded 80->96(->104)
    __shared__ ushortT Ws[96 * 104];    // W1T tile; Hs aliases rows 0..63
    __shared__ ushortT W2s[80 * 104];   // W2T tile
    ushortT* Hs = Ws;

    int t    = threadIdx.x;
    int wave = t >> 6, lane = t & 63;
    int qd   = lane >> 4, ln16 = lane & 15;
    size_t rowbase = (size_t)blockIdx.x * 64;

    for (int u = t; u < 64 * 80; u += 256) {
        int i = u / 80, c = u - i * 80;
        Xs[i * 104 + c] = f2bf(hdn_in[(rowbase + i) * HD + c]);
    }
    for (int u = t; u < 64 * 16; u += 256) {
        int i = u >> 4, c = u & 15;
        Xs[i * 104 + 80 + c] = 0;
    }

    f4 acc[5];
#pragma unroll
    for (int ot = 0; ot < 5; ++ot) acc[ot] = (f4)0.f;

    const uint* W1T32 = (const uint*)W1T;
    const uint* W2T32 = (const uint*)W2T;
    uint* Wsu  = (uint*)Ws;
    uint* W2su = (uint*)W2s;

    for (int jt = 0; jt < DH; jt += 96) {
        for (int u = t; u < 96 * 48; u += 256) {
            int n = u / 48, k2 = u - n * 48;
            Wsu[n * 52 + k2] = W1T32[(size_t)(jt + n) * 48 + k2];
        }
        for (int u = t; u < 80 * 48; u += 256) {
            int n = u / 48, k2 = u - n * 48;
            W2su[n * 52 + k2] = W2T32[(size_t)n * 240 + (jt >> 1) + k2];
        }
        __syncthreads();

        bfrag a[3];
#pragma unroll
        for (int ks = 0; ks < 3; ++ks)
            a[ks] = *(const bfrag*)&Xs[(wave * 16 + ln16) * 104 + ks * 32 + qd * 8];
        f4 hc[6];
#pragma unroll
        for (int nt = 0; nt < 6; ++nt) {
            f4 c = (f4)0.f;
#pragma unroll
            for (int ks = 0; ks < 3; ++ks) {
                bfrag b = *(const bfrag*)&Ws[(nt * 16 + ln16) * 104 + ks * 32 + qd * 8];
                c = __builtin_amdgcn_mfma_f32_16x16x32_bf16(a[ks], b, c, 0, 0, 0);
            }
            hc[nt] = c;
        }
        __syncthreads();

#pragma unroll
        for (int nt = 0; nt < 6; ++nt) {
            float bv = b1[jt + nt * 16 + ln16];
#pragma unroll
            for (int r = 0; r < 4; ++r) {
                float v = hc[nt][r] + bv;
                v = (v > 0.f) ? v : 0.01f * v;
                Hs[(wave * 16 + qd * 4 + r) * 104 + nt * 16 + ln16] = f2bf(v);
            }
        }
        __syncthreads();

        bfrag a2[3];
#pragma unroll
        for (int ks = 0; ks < 3; ++ks)
            a2[ks] = *(const bfrag*)&Hs[(wave * 16 + ln16) * 104 + ks * 32 + qd * 8];
#pragma unroll
        for (int ot = 0; ot < 5; ++ot) {
            f4 c = acc[ot];
#pragma unroll
            for (int ks = 0; ks < 3; ++ks) {
                bfrag b = *(const bfrag*)&W2s[(ot * 16 + ln16) * 104 + ks * 32 + qd * 8];
                c = __builtin_amdgcn_mfma_f32_16x16x32_bf16(a2[ks], b, c, 0, 0, 0);
            }
            acc[ot] = c;
        }
        __syncthreads();
    }

    float tv[5][4];
#pragma unroll
    for (int ot = 0; ot < 5; ++ot) {
        int col = ot * 16 + ln16;
        float b2v = b2[col];
#pragma unroll
        for (int r = 0; r < 4; ++r) {
            size_t row = rowbase + wave * 16 + qd * 4 + r;
            tv[ot][r] = acc[ot][r] + b2v + res[row * HD + col];
        }
    }
#pragma unroll
    for (int r = 0; r < 4; ++r) {
        float s = 0.f, sq = 0.f;
#pragma unroll
        for (int ot = 0; ot < 5; ++ot) { s += tv[ot][r]; sq += tv[ot][r] * tv[ot][r]; }
#pragma unroll
        for (int o = 8; o; o >>= 1) { s += __shfl_xor(s, o); sq += __shfl_xor(sq, o); }
        float m    = s * (1.f / 80.f);
        float var  = sq * (1.f / 80.f) - m * m;
        float rstd = rsqrtf(var + 1e-5f);
        size_t row = rowbase + wave * 16 + qd * 4 + r;
#pragma unroll
        for (int ot = 0; ot < 5; ++ot) {
            int col = ot * 16 + ln16;
            hdn_out[row * HD + col] = (tv[ot][r] - m) * rstd * g[col] + be[col];
        }
    }
}

// ---------------------------------------------------------------------------
// Kernel 6: mean over heads -> (B, S, HD)
__global__ __launch_bounds__(256) void k_mean(const float* __restrict__ hdn,
                                              float* __restrict__ out) {
    int idx = blockIdx.x * 256 + threadIdx.x;
    int b   = idx / (SS * HD);
    int sd  = idx - b * (SS * HD);
    float s = 0.f;
#pragma unroll
    for (int h = 0; h < HH; ++h)
        s += hdn[((size_t)(b * HH + h)) * (SS * HD) + sd];
    out[idx] = s * 0.125f;
}

// ---------------------------------------------------------------------------
extern "C" void kernel_launch(void* const* d_in, const int* in_sizes, int n_in,
                              void* d_out, int out_size, void* d_ws, size_t ws_size,
                              hipStream_t stream) {
    (void)in_sizes; (void)n_in; (void)out_size; (void)ws_size;
    const float* x      = (const float*)d_in[0];
    const float* W1     = (const float*)d_in[1];
    const float* b1     = (const float*)d_in[2];
    const float* W2     = (const float*)d_in[3];
    const float* b2     = (const float*)d_in[4];
    const float* gamma  = (const float*)d_in[5];
    const float* beta   = (const float*)d_in[6];
    const float* slopes = (const float*)d_in[7];
    float* out = (float*)d_out;
    float* ws  = (float*)d_ws;

    float* res = ws;                 // 5,242,880 floats
    float* hdn = ws + ROWSZ;         // 5,242,880
    float* oin = ws + 2 * ROWSZ;     // 5,242,880
    float* kv  = ws + 3 * ROWSZ;     // 32*16*6400 = 3,276,800

    // bf16 transposed weights live in d_out scratch (k_mean overwrites it last)
    ushortT* W1T = (ushortT*)d_out;            // 480*96
    ushortT* W2T = W1T + 480 * 96;             // 80*480

    k_prep<<<(480 * 96 + 80 * 480 + 255) / 256, 256, 0, stream>>>(W1, W2, W1T, W2T);
    k_ln0<<<NROW / 4, 256, 0, stream>>>(x, gamma, beta, hdn, res);
    for (int it = 0; it < 2; ++it) {
        k_attn_a<<<BB * HH * NC, 256, 0, stream>>>(hdn, slopes, oin, kv);
        k_scan<<<(BB * HH * HD * HD) / 256, 256, 0, stream>>>(kv, slopes);
        k_attn_b<<<BB * HH * NC, 256, 0, stream>>>(hdn, oin, kv, res, slopes, gamma, beta, hdn);
        k_ffn<<<NROW / 64, 256, 0, stream>>>(hdn, W1T, b1, W2T, b2, res, gamma, beta, hdn);
    }
    k_mean<<<(BB * SS * HD) / 256, 256, 0, stream>>>(hdn, out);
}

// Round 5
// 242.037 us; speedup vs baseline: 4.9736x; 1.3700x over previous
//
#include <hip/hip_runtime.h>
#include <hip/hip_bf16.h>

// Problem constants
#define BB 4
#define HH 8
#define SS 2048
#define HD 80
#define CC 128
#define NC 16
#define DH 480           // MULT*HD
#define NROW (BB*HH*SS)  // 65536
#define ROWSZ ((size_t)NROW * HD)  // 5,242,880 floats per tensor buffer

typedef unsigned short ushortT;
typedef __attribute__((ext_vector_type(8))) short bfrag;   // 8 bf16 = 4 VGPRs
typedef __attribute__((ext_vector_type(4))) float f4;
typedef __attribute__((ext_vector_type(4))) unsigned int u4;

__device__ __forceinline__ ushortT f2bf(float f) {
    __hip_bfloat16 h = __float2bfloat16(f);   // RNE
    ushortT u; __builtin_memcpy(&u, &h, 2); return u;
}
__device__ __forceinline__ float bf2f(ushortT u) {
    unsigned int x = ((unsigned int)u) << 16;
    float f; __builtin_memcpy(&f, &x, 4); return f;
}

// ---------------------------------------------------------------------------
// Kernel 0: prep — transpose + bf16-cast W1 (-> W1T[480][96], K zero-padded)
// and W2 (-> W2T[80][480]). Outputs live in d_out tail (k_mean overwrites last).
__global__ __launch_bounds__(256) void k_prep(const float* __restrict__ W1,
                                              const float* __restrict__ W2,
                                              ushortT* __restrict__ W1T,
                                              ushortT* __restrict__ W2T) {
    int idx = blockIdx.x * 256 + threadIdx.x;
    if (idx < 480 * 96) {
        int n = idx / 96, k = idx - n * 96;
        float v = (k < HD) ? W1[k * DH + n] : 0.f;
        W1T[idx] = f2bf(v);
    } else if (idx < 480 * 96 + 80 * 480) {
        int j = idx - 480 * 96;
        int n = j / DH, k = j - n * DH;
        W2T[j] = f2bf(W2[k * HD + n]);
    }
}

// ---------------------------------------------------------------------------
// Kernel 1: first LN (x reshaped is a pure reinterpret: row = (b*8+h)*2048+s)
__global__ __launch_bounds__(256) void k_ln0(const float* __restrict__ x,
                                             const float* __restrict__ g,
                                             const float* __restrict__ be,
                                             float* __restrict__ hdn,
                                             float* __restrict__ res) {
    int row  = blockIdx.x * 4 + (threadIdx.x >> 6);
    int lane = threadIdx.x & 63;
    const float* xr = x + (size_t)row * HD;
    float v0 = xr[lane];
    float v1 = (lane < 16) ? xr[64 + lane] : 0.f;
    float s  = v0 + v1;
    float sq = v0 * v0 + v1 * v1;
#pragma unroll
    for (int o = 32; o; o >>= 1) { s += __shfl_xor(s, o); sq += __shfl_xor(sq, o); }
    float m    = s * (1.f / 80.f);
    float var  = sq * (1.f / 80.f) - m * m;
    float rstd = rsqrtf(var + 1e-5f);
    size_t base = (size_t)row * HD;
    float y0 = (v0 - m) * rstd * g[lane] + be[lane];
    hdn[base + lane] = y0; res[base + lane] = y0;
    if (lane < 16) {
        float y1 = (v1 - m) * rstd * g[64 + lane] + be[64 + lane];
        hdn[base + 64 + lane] = y1; res[base + 64 + lane] = y1;
    }
}

// ---------------------------------------------------------------------------
// Kernel 2: per-chunk intra attention + chunk KV, all via bf16 MFMA.
__global__ __launch_bounds__(256) void k_attn_a(const float* __restrict__ hdn,
                                                const float* __restrict__ slopes,
                                                float* __restrict__ oin,
                                                float* __restrict__ ckv) {
    __shared__ ushortT Xs[CC * 104];   // 128 rows x 96(k-pad, stride 104)
    __shared__ ushortT SC[CC * 40];    // 128 rows x 32(pad 40) score block, A-layout
    __shared__ ushortT XT[HD * 136];   // 80 d-rows x 128 j (stride 136)
    __shared__ float dec[CC];          // exp(-sl*delta)
    __shared__ float sqk[CC];          // sqrt(kd[j]) = exp(-0.5*sl*(128-j))

    int t    = threadIdx.x;
    int wave = t >> 6, lane = t & 63;
    int quad = lane >> 4, ln16 = lane & 15;
    int bk = blockIdx.x;
    int bh = bk >> 4;
    int n  = bk & 15;
    float sl = slopes[bh & 7];

    size_t chunkrow = (size_t)bh * SS + (size_t)n * CC;
    const float* xb = hdn + chunkrow * HD;

    if (t < CC) {
        dec[t] = expf(-sl * (float)t);
        sqk[t] = expf(-0.5f * sl * (float)(CC - t));
    }
    for (int u = t; u < CC * HD; u += 256) {
        int i = u / HD, c = u - i * HD;
        ushortT v = f2bf(xb[u]);
        Xs[i * 104 + c] = v;
        XT[c * 136 + i] = v;
    }
    for (int u = t; u < CC * 16; u += 256) {
        int i = u >> 4, c = u & 15;
        Xs[i * 104 + 80 + c] = 0;
    }
    __syncthreads();

    bfrag a[2][3];
#pragma unroll
    for (int rt = 0; rt < 2; ++rt) {
        int mt = wave + rt * 4;
#pragma unroll
        for (int ks = 0; ks < 3; ++ks)
            a[rt][ks] = *(const bfrag*)&Xs[(mt * 16 + ln16) * 104 + ks * 32 + quad * 8];
    }

    f4 oacc[2][5];
#pragma unroll
    for (int rt = 0; rt < 2; ++rt)
#pragma unroll
        for (int ot = 0; ot < 5; ++ot) oacc[rt][ot] = (f4)0.f;

    for (int jt = 0; jt < 4; ++jt) {
        if (wave + 4 < 2 * jt) continue;
        int j0 = jt * 32;
        bfrag bq[2][3];
#pragma unroll
        for (int nt = 0; nt < 2; ++nt)
#pragma unroll
            for (int ks = 0; ks < 3; ++ks)
                bq[nt][ks] = *(const bfrag*)&Xs[(j0 + nt * 16 + ln16) * 104 + ks * 32 + quad * 8];

#pragma unroll
        for (int rt = 0; rt < 2; ++rt) {
            int mt = wave + rt * 4;
            if (mt < 2 * jt) continue;
            int i_base = mt * 16;
            f4 c0 = (f4)0.f, c1 = (f4)0.f;
#pragma unroll
            for (int ks = 0; ks < 3; ++ks) {
                c0 = __builtin_amdgcn_mfma_f32_16x16x32_bf16(a[rt][ks], bq[0][ks], c0, 0, 0, 0);
                c1 = __builtin_amdgcn_mfma_f32_16x16x32_bf16(a[rt][ks], bq[1][ks], c1, 0, 0, 0);
            }
#pragma unroll
            for (int r = 0; r < 4; ++r) {
                int i = i_base + quad * 4 + r;
                int d0 = i - (j0 + ln16);
                int d1 = d0 - 16;
                float f0 = (d0 >= 0) ? dec[d0] : 0.f;
                float f1 = (d1 >= 0) ? dec[d1] : 0.f;
                SC[i * 40 + ln16]      = f2bf(c0[r] * f0);
                SC[i * 40 + 16 + ln16] = f2bf(c1[r] * f1);
            }
            bfrag a2 = *(const bfrag*)&SC[(i_base + ln16) * 40 + quad * 8];
#pragma unroll
            for (int ot = 0; ot < 5; ++ot) {
                bfrag bv = *(const bfrag*)&XT[(ot * 16 + ln16) * 136 + j0 + quad * 8];
                oacc[rt][ot] = __builtin_amdgcn_mfma_f32_16x16x32_bf16(a2, bv, oacc[rt][ot], 0, 0, 0);
            }
        }
    }

#pragma unroll
    for (int rt = 0; rt < 2; ++rt) {
        int i_base = (wave + rt * 4) * 16;
#pragma unroll
        for (int r = 0; r < 4; ++r) {
            size_t grow = (chunkrow + i_base + quad * 4 + r) * HD;
#pragma unroll
            for (int ot = 0; ot < 5; ++ot)
                oin[grow + ot * 16 + ln16] = oacc[rt][ot][r];
        }
    }

    __syncthreads();
    for (int u = t; u < HD * CC; u += 256) {
        int e = u >> 7, j = u & 127;
        int idx = e * 136 + j;
        XT[idx] = f2bf(bf2f(XT[idx]) * sqk[j]);
    }
    __syncthreads();

    float* kvout = ckv + (size_t)bk * (HD * HD);
    for (int p = wave; p < 25; p += 4) {
        int me = p / 5, ne = p - me * 5;
        f4 c = (f4)0.f;
#pragma unroll
        for (int ks = 0; ks < 4; ++ks) {
            bfrag av = *(const bfrag*)&XT[(me * 16 + ln16) * 136 + ks * 32 + quad * 8];
            bfrag bv = *(const bfrag*)&XT[(ne * 16 + ln16) * 136 + ks * 32 + quad * 8];
            c = __builtin_amdgcn_mfma_f32_16x16x32_bf16(av, bv, c, 0, 0, 0);
        }
#pragma unroll
        for (int r = 0; r < 4; ++r)
            kvout[(me * 16 + quad * 4 + r) * HD + ne * 16 + ln16] = c[r];
    }
}

// ---------------------------------------------------------------------------
// Kernel 3: in-place decay prefix-scan over chunk KVs.
__global__ __launch_bounds__(256) void k_scan(float* __restrict__ kv,
                                              const float* __restrict__ slopes) {
    int idx = blockIdx.x * 256 + threadIdx.x;
    int bh  = idx / (HD * HD);
    int ed  = idx - bh * (HD * HD);
    float bd = expf(-slopes[bh & 7] * (float)CC);
    size_t base = (size_t)bh * NC * (HD * HD) + ed;
    float st = 0.f;
#pragma unroll
    for (int n = 0; n < NC; ++n) {
        size_t p = base + (size_t)n * (HD * HD);
        float cv = kv[p];
        kv[p] = st;
        st = bd * st + cv;
    }
}

// ---------------------------------------------------------------------------
// Kernel 4: inter-chunk term via bf16 MFMA, fused + intra + residual + LN.
__global__ __launch_bounds__(256) void k_attn_b(const float* __restrict__ hdn_in,
                                                const float* __restrict__ oin,
                                                const float* __restrict__ kvs,
                                                const float* __restrict__ res,
                                                const float* __restrict__ slopes,
                                                const float* __restrict__ g,
                                                const float* __restrict__ be,
                                                float* __restrict__ hdn_out) {
    __shared__ ushortT Qs[CC * 104];     // 128 rows x (96 k, padded stride 104)
    __shared__ ushortT KVT[80 * 104];    // 80 d-rows x (96 e, padded stride 104)

    int t    = threadIdx.x;
    int wave = t >> 6, lane = t & 63;
    int qd   = lane >> 4, ln16 = lane & 15;
    int bk = blockIdx.x;
    int bh = bk >> 4;
    int n  = bk & 15;
    float sl = slopes[bh & 7];

    size_t chunkrow = (size_t)bh * SS + (size_t)n * CC;
    const float* xb = hdn_in + chunkrow * HD;
    const float* KV = kvs + ((size_t)bh * NC + n) * (HD * HD);

    for (int u = t; u < CC * HD; u += 256) {
        int i = u / HD, c = u - i * HD;
        Qs[i * 104 + c] = f2bf(xb[u]);
    }
    for (int u = t; u < CC * 16; u += 256) {
        int i = u >> 4, c = u & 15;
        Qs[i * 104 + 80 + c] = 0;
    }
    for (int u = t; u < HD * HD; u += 256) {
        int e = u / HD, d = u - e * HD;
        KVT[d * 104 + e] = f2bf(KV[u]);
    }
    for (int u = t; u < HD * 16; u += 256) {
        int d = u >> 4, e = u & 15;
        KVT[d * 104 + 80 + e] = 0;
    }
    __syncthreads();

    int m0 = wave * 32;
    bfrag a[2][3];
#pragma unroll
    for (int rt = 0; rt < 2; ++rt)
#pragma unroll
        for (int ks = 0; ks < 3; ++ks)
            a[rt][ks] = *(const bfrag*)&Qs[(m0 + rt * 16 + ln16) * 104 + ks * 32 + qd * 8];

    f4 acc[2][5];
#pragma unroll
    for (int ot = 0; ot < 5; ++ot) {
#pragma unroll
        for (int rt = 0; rt < 2; ++rt) acc[rt][ot] = (f4)0.f;
#pragma unroll
        for (int ks = 0; ks < 3; ++ks) {
            bfrag b = *(const bfrag*)&KVT[(ot * 16 + ln16) * 104 + ks * 32 + qd * 8];
#pragma unroll
            for (int rt = 0; rt < 2; ++rt)
                acc[rt][ot] = __builtin_amdgcn_mfma_f32_16x16x32_bf16(a[rt][ks], b, acc[rt][ot], 0, 0, 0);
        }
    }

#pragma unroll
    for (int rt = 0; rt < 2; ++rt) {
#pragma unroll
        for (int r = 0; r < 4; ++r) {
            int i = m0 + rt * 16 + qd * 4 + r;
            float qdec = expf(-sl * (float)i);
            size_t grow = (chunkrow + i) * HD;
            float tv[5];
            float s = 0.f, sq = 0.f;
#pragma unroll
            for (int ot = 0; ot < 5; ++ot) {
                int col = ot * 16 + ln16;
                tv[ot] = oin[grow + col] + qdec * acc[rt][ot][r] + res[grow + col];
                s += tv[ot]; sq += tv[ot] * tv[ot];
            }
#pragma unroll
            for (int o = 8; o; o >>= 1) { s += __shfl_xor(s, o); sq += __shfl_xor(sq, o); }
            float m    = s * (1.f / 80.f);
            float var  = sq * (1.f / 80.f) - m * m;
            float rstd = rsqrtf(var + 1e-5f);
#pragma unroll
            for (int ot = 0; ot < 5; ++ot) {
                int col = ot * 16 + ln16;
                hdn_out[grow + col] = (tv[ot] - m) * rstd * g[col] + be[col];
            }
        }
    }
}

// ---------------------------------------------------------------------------
// Kernel 5: FFN via bf16 MFMA, 128 rows/block, vectorized staging,
// 3 barriers per hidden chunk. Hs aliases the W1 tile (wave-private rows, so
// no barrier between Hs writes and GEMM2 reads — same-wave ds ordering).
__global__ __launch_bounds__(256, 2) void k_ffn(const float* __restrict__ hdn_in,
                                                const ushortT* __restrict__ W1T,
                                                const float* __restrict__ b1,
                                                const ushortT* __restrict__ W2T,
                                                const float* __restrict__ b2,
                                                const float* __restrict__ res,
                                                const float* __restrict__ g,
                                                const float* __restrict__ be,
                                                float* __restrict__ hdn_out) {
    __shared__ ushortT Xs[128 * 104];    // 26.6 KB: X tile, K padded 80->96
    __shared__ ushortT WH[128 * 104];    // 26.6 KB: W1 tile (rows 0..95) / Hs alias (128 rows)
    __shared__ ushortT W2s[80 * 104];    // 16.6 KB
    // total 69.9 KB -> 2 blocks/CU

    int t    = threadIdx.x;
    int wave = t >> 6, lane = t & 63;
    int qd   = lane >> 4, ln16 = lane & 15;
    size_t rowbase = (size_t)blockIdx.x * 128;

    // stage X vectorized: 128 rows x 20 float4; convert to bf16, ds_write_b64
    {
        const f4* xin = (const f4*)(hdn_in + rowbase * HD);
        for (int u = t; u < 128 * 20; u += 256) {
            int i = u / 20, c4 = u - i * 20;
            f4 v = xin[u];
            ushortT tmp[4];
#pragma unroll
            for (int z = 0; z < 4; ++z) tmp[z] = f2bf(v[z]);
            *(double*)&Xs[i * 104 + c4 * 4] = *(double*)tmp;   // 8B write
        }
        for (int u = t; u < 128 * 16; u += 256) {
            int i = u >> 4, c = u & 15;
            Xs[i * 104 + 80 + c] = 0;
        }
    }

    f4 acc[2][5];
#pragma unroll
    for (int rt = 0; rt < 2; ++rt)
#pragma unroll
        for (int ot = 0; ot < 5; ++ot) acc[rt][ot] = (f4)0.f;

    const u4* W1T16 = (const u4*)W1T;    // 480 rows x 12 u4
    const u4* W2T16 = (const u4*)W2T;    // 80 rows x 60 u4
    u4* WH16  = (u4*)WH;                 // row stride 13 u4 (=104 ushort)
    u4* W2s16 = (u4*)W2s;

    for (int jt = 0; jt < DH; jt += 96) {
        __syncthreads();   // protects Xs (iter 0) / WH+W2s from previous iter reads
        // stage W1 chunk rows jt..jt+95 (96 x 12 u4) and W2 chunk (80 x 12 u4)
        for (int u = t; u < 96 * 12; u += 256) {
            int n = u / 12, k = u - n * 12;
            WH16[n * 13 + k] = W1T16[(size_t)(jt + n) * 12 + k];
        }
        for (int u = t; u < 80 * 12; u += 256) {
            int n = u / 12, k = u - n * 12;
            W2s16[n * 13 + k] = W2T16[(size_t)n * 60 + (jt >> 3) + k];
        }
        __syncthreads();

        // GEMM1: H chunk = X @ W1c. Each wave: 2 m-tiles (rows wave*32..+31)
        f4 hc[2][6];
#pragma unroll
        for (int rt = 0; rt < 2; ++rt)
#pragma unroll
            for (int nt = 0; nt < 6; ++nt) hc[rt][nt] = (f4)0.f;
#pragma unroll
        for (int ks = 0; ks < 3; ++ks) {
            bfrag a0 = *(const bfrag*)&Xs[((wave * 2 + 0) * 16 + ln16) * 104 + ks * 32 + qd * 8];
            bfrag a1 = *(const bfrag*)&Xs[((wave * 2 + 1) * 16 + ln16) * 104 + ks * 32 + qd * 8];
#pragma unroll
            for (int nt = 0; nt < 6; ++nt) {
                bfrag b = *(const bfrag*)&WH[(nt * 16 + ln16) * 104 + ks * 32 + qd * 8];
                hc[0][nt] = __builtin_amdgcn_mfma_f32_16x16x32_bf16(a0, b, hc[0][nt], 0, 0, 0);
                hc[1][nt] = __builtin_amdgcn_mfma_f32_16x16x32_bf16(a1, b, hc[1][nt], 0, 0, 0);
            }
        }
        __syncthreads();   // all waves done reading W1 tile (WH) before Hs overwrite

        // leaky-relu + bf16 -> Hs (aliases WH; rows wave-private)
#pragma unroll
        for (int rt = 0; rt < 2; ++rt) {
            int mrow = (wave * 2 + rt) * 16 + qd * 4;
#pragma unroll
            for (int nt = 0; nt < 6; ++nt) {
                float bv = b1[jt + nt * 16 + ln16];
#pragma unroll
                for (int r = 0; r < 4; ++r) {
                    float v = hc[rt][nt][r] + bv;
                    v = (v > 0.f) ? v : 0.01f * v;
                    WH[(mrow + r) * 104 + nt * 16 + ln16] = f2bf(v);
                }
            }
        }
        // GEMM2: acc += H chunk @ W2c (no barrier: Hs rows written by this wave)
#pragma unroll
        for (int ks = 0; ks < 3; ++ks) {
            bfrag a0 = *(const bfrag*)&WH[((wave * 2 + 0) * 16 + ln16) * 104 + ks * 32 + qd * 8];
            bfrag a1 = *(const bfrag*)&WH[((wave * 2 + 1) * 16 + ln16) * 104 + ks * 32 + qd * 8];
#pragma unroll
            for (int ot = 0; ot < 5; ++ot) {
                bfrag b = *(const bfrag*)&W2s[(ot * 16 + ln16) * 104 + ks * 32 + qd * 8];
                acc[0][ot] = __builtin_amdgcn_mfma_f32_16x16x32_bf16(a0, b, acc[0][ot], 0, 0, 0);
                acc[1][ot] = __builtin_amdgcn_mfma_f32_16x16x32_bf16(a1, b, acc[1][ot], 0, 0, 0);
            }
        }
    }

    // epilogue: + b2 + residual, LN per row (C-layout: row=qd*4+r, col=ot*16+ln16)
#pragma unroll
    for (int rt = 0; rt < 2; ++rt) {
        int mbase = (wave * 2 + rt) * 16 + qd * 4;
#pragma unroll
        for (int r = 0; r < 4; ++r) {
            size_t row = rowbase + mbase + r;
            float tv[5];
            float s = 0.f, sq = 0.f;
#pragma unroll
            for (int ot = 0; ot < 5; ++ot) {
                int col = ot * 16 + ln16;
                tv[ot] = acc[rt][ot][r] + b2[col] + res[row * HD + col];
                s += tv[ot]; sq += tv[ot] * tv[ot];
            }
#pragma unroll
            for (int o = 8; o; o >>= 1) { s += __shfl_xor(s, o); sq += __shfl_xor(sq, o); }
            float m    = s * (1.f / 80.f);
            float var  = sq * (1.f / 80.f) - m * m;
            float rstd = rsqrtf(var + 1e-5f);
#pragma unroll
            for (int ot = 0; ot < 5; ++ot) {
                int col = ot * 16 + ln16;
                hdn_out[row * HD + col] = (tv[ot] - m) * rstd * g[col] + be[col];
            }
        }
    }
}

// ---------------------------------------------------------------------------
// Kernel 6: mean over heads -> (B, S, HD)
__global__ __launch_bounds__(256) void k_mean(const float* __restrict__ hdn,
                                              float* __restrict__ out) {
    int idx = blockIdx.x * 256 + threadIdx.x;
    int b   = idx / (SS * HD);
    int sd  = idx - b * (SS * HD);
    float s = 0.f;
#pragma unroll
    for (int h = 0; h < HH; ++h)
        s += hdn[((size_t)(b * HH + h)) * (SS * HD) + sd];
    out[idx] = s * 0.125f;
}

// ---------------------------------------------------------------------------
extern "C" void kernel_launch(void* const* d_in, const int* in_sizes, int n_in,
                              void* d_out, int out_size, void* d_ws, size_t ws_size,
                              hipStream_t stream) {
    (void)in_sizes; (void)n_in; (void)out_size; (void)ws_size;
    const float* x      = (const float*)d_in[0];
    const float* W1     = (const float*)d_in[1];
    const float* b1     = (const float*)d_in[2];
    const float* W2     = (const float*)d_in[3];
    const float* b2     = (const float*)d_in[4];
    const float* gamma  = (const float*)d_in[5];
    const float* beta   = (const float*)d_in[6];
    const float* slopes = (const float*)d_in[7];
    float* out = (float*)d_out;
    float* ws  = (float*)d_ws;

    float* res = ws;                 // 5,242,880 floats
    float* hdn = ws + ROWSZ;         // 5,242,880
    float* oin = ws + 2 * ROWSZ;     // 5,242,880
    float* kv  = ws + 3 * ROWSZ;     // 32*16*6400 = 3,276,800

    // bf16 transposed weights live in d_out scratch (k_mean overwrites it last)
    ushortT* W1T = (ushortT*)d_out;            // 480*96
    ushortT* W2T = W1T + 480 * 96;             // 80*480

    k_prep<<<(480 * 96 + 80 * 480 + 255) / 256, 256, 0, stream>>>(W1, W2, W1T, W2T);
    k_ln0<<<NROW / 4, 256, 0, stream>>>(x, gamma, beta, hdn, res);
    for (int it = 0; it < 2; ++it) {
        k_attn_a<<<BB * HH * NC, 256, 0, stream>>>(hdn, slopes, oin, kv);
        k_scan<<<(BB * HH * HD * HD) / 256, 256, 0, stream>>>(kv, slopes);
        k_attn_b<<<BB * HH * NC, 256, 0, stream>>>(hdn, oin, kv, res, slopes, gamma, beta, hdn);
        k_ffn<<<NROW / 128, 256, 0, stream>>>(hdn, W1T, b1, W2T, b2, res, gamma, beta, hdn);
    }
    k_mean<<<(BB * SS * HD) / 256, 256, 0, stream>>>(hdn, out);
}

// Round 9
// 240.856 us; speedup vs baseline: 4.9980x; 1.0049x over previous
//
#include <hip/hip_runtime.h>
#include <hip/hip_bf16.h>

// Problem constants
#define BB 4
#define HH 8
#define SS 2048
#define HD 80
#define CC 128
#define NC 16
#define DH 480           // MULT*HD
#define NROW (BB*HH*SS)  // 65536
#define ROWSZ ((size_t)NROW * HD)  // 5,242,880 floats per tensor buffer

typedef unsigned short ushortT;
typedef __attribute__((ext_vector_type(8))) short bfrag;   // 8 bf16 = 4 VGPRs
typedef __attribute__((ext_vector_type(4))) float f4;
typedef __attribute__((ext_vector_type(4))) unsigned int u4;

__device__ __forceinline__ ushortT f2bf(float f) {
    __hip_bfloat16 h = __float2bfloat16(f);   // RNE
    ushortT u; __builtin_memcpy(&u, &h, 2); return u;
}
__device__ __forceinline__ float bf2f(ushortT u) {
    unsigned int x = ((unsigned int)u) << 16;
    float f; __builtin_memcpy(&f, &x, 4); return f;
}

// ---------------------------------------------------------------------------
// Kernel 0: prep — transpose + bf16-cast W1 (-> W1T[480][96], K zero-padded)
// and W2 (-> W2T[80][480]). Outputs live in d_out tail (k_mean overwrites last).
__global__ __launch_bounds__(256) void k_prep(const float* __restrict__ W1,
                                              const float* __restrict__ W2,
                                              ushortT* __restrict__ W1T,
                                              ushortT* __restrict__ W2T) {
    int idx = blockIdx.x * 256 + threadIdx.x;
    if (idx < 480 * 96) {
        int n = idx / 96, k = idx - n * 96;
        float v = (k < HD) ? W1[k * DH + n] : 0.f;
        W1T[idx] = f2bf(v);
    } else if (idx < 480 * 96 + 80 * 480) {
        int j = idx - 480 * 96;
        int n = j / DH, k = j - n * DH;
        W2T[j] = f2bf(W2[k * HD + n]);
    }
}

// ---------------------------------------------------------------------------
// Kernel 1: first LN (x reshaped is a pure reinterpret: row = (b*8+h)*2048+s)
__global__ __launch_bounds__(256) void k_ln0(const float* __restrict__ x,
                                             const float* __restrict__ g,
                                             const float* __restrict__ be,
                                             float* __restrict__ hdn,
                                             float* __restrict__ res) {
    int row  = blockIdx.x * 4 + (threadIdx.x >> 6);
    int lane = threadIdx.x & 63;
    const float* xr = x + (size_t)row * HD;
    float v0 = xr[lane];
    float v1 = (lane < 16) ? xr[64 + lane] : 0.f;
    float s  = v0 + v1;
    float sq = v0 * v0 + v1 * v1;
#pragma unroll
    for (int o = 32; o; o >>= 1) { s += __shfl_xor(s, o); sq += __shfl_xor(sq, o); }
    float m    = s * (1.f / 80.f);
    float var  = sq * (1.f / 80.f) - m * m;
    float rstd = rsqrtf(var + 1e-5f);
    size_t base = (size_t)row * HD;
    float y0 = (v0 - m) * rstd * g[lane] + be[lane];
    hdn[base + lane] = y0; res[base + lane] = y0;
    if (lane < 16) {
        float y1 = (v1 - m) * rstd * g[64 + lane] + be[64 + lane];
        hdn[base + 64 + lane] = y1; res[base + 64 + lane] = y1;
    }
}

// ---------------------------------------------------------------------------
// Kernel 2: per-chunk intra attention + chunk KV, all via bf16 MFMA.
__global__ __launch_bounds__(256) void k_attn_a(const float* __restrict__ hdn,
                                                const float* __restrict__ slopes,
                                                float* __restrict__ oin,
                                                float* __restrict__ ckv) {
    __shared__ ushortT Xs[CC * 104];   // 128 rows x 96(k-pad, stride 104)
    __shared__ ushortT SC[CC * 40];    // 128 rows x 32(pad 40) score block, A-layout
    __shared__ ushortT XT[HD * 136];   // 80 d-rows x 128 j (stride 136)
    __shared__ float dec[CC];          // exp(-sl*delta)
    __shared__ float sqk[CC];          // sqrt(kd[j]) = exp(-0.5*sl*(128-j))

    int t    = threadIdx.x;
    int wave = t >> 6, lane = t & 63;
    int quad = lane >> 4, ln16 = lane & 15;
    int bk = blockIdx.x;
    int bh = bk >> 4;
    int n  = bk & 15;
    float sl = slopes[bh & 7];

    size_t chunkrow = (size_t)bh * SS + (size_t)n * CC;
    const float* xb = hdn + chunkrow * HD;

    if (t < CC) {
        dec[t] = expf(-sl * (float)t);
        sqk[t] = expf(-0.5f * sl * (float)(CC - t));
    }
    for (int u = t; u < CC * HD; u += 256) {
        int i = u / HD, c = u - i * HD;
        ushortT v = f2bf(xb[u]);
        Xs[i * 104 + c] = v;
        XT[c * 136 + i] = v;
    }
    for (int u = t; u < CC * 16; u += 256) {
        int i = u >> 4, c = u & 15;
        Xs[i * 104 + 80 + c] = 0;
    }
    __syncthreads();

    bfrag a[2][3];
#pragma unroll
    for (int rt = 0; rt < 2; ++rt) {
        int mt = wave + rt * 4;
#pragma unroll
        for (int ks = 0; ks < 3; ++ks)
            a[rt][ks] = *(const bfrag*)&Xs[(mt * 16 + ln16) * 104 + ks * 32 + quad * 8];
    }

    f4 oacc[2][5];
#pragma unroll
    for (int rt = 0; rt < 2; ++rt)
#pragma unroll
        for (int ot = 0; ot < 5; ++ot) oacc[rt][ot] = (f4)0.f;

    for (int jt = 0; jt < 4; ++jt) {
        if (wave + 4 < 2 * jt) continue;
        int j0 = jt * 32;
        bfrag bq[2][3];
#pragma unroll
        for (int nt = 0; nt < 2; ++nt)
#pragma unroll
            for (int ks = 0; ks < 3; ++ks)
                bq[nt][ks] = *(const bfrag*)&Xs[(j0 + nt * 16 + ln16) * 104 + ks * 32 + quad * 8];

#pragma unroll
        for (int rt = 0; rt < 2; ++rt) {
            int mt = wave + rt * 4;
            if (mt < 2 * jt) continue;
            int i_base = mt * 16;
            f4 c0 = (f4)0.f, c1 = (f4)0.f;
#pragma unroll
            for (int ks = 0; ks < 3; ++ks) {
                c0 = __builtin_amdgcn_mfma_f32_16x16x32_bf16(a[rt][ks], bq[0][ks], c0, 0, 0, 0);
                c1 = __builtin_amdgcn_mfma_f32_16x16x32_bf16(a[rt][ks], bq[1][ks], c1, 0, 0, 0);
            }
#pragma unroll
            for (int r = 0; r < 4; ++r) {
                int i = i_base + quad * 4 + r;
                int d0 = i - (j0 + ln16);
                int d1 = d0 - 16;
                float f0 = (d0 >= 0) ? dec[d0] : 0.f;
                float f1 = (d1 >= 0) ? dec[d1] : 0.f;
                SC[i * 40 + ln16]      = f2bf(c0[r] * f0);
                SC[i * 40 + 16 + ln16] = f2bf(c1[r] * f1);
            }
            bfrag a2 = *(const bfrag*)&SC[(i_base + ln16) * 40 + quad * 8];
#pragma unroll
            for (int ot = 0; ot < 5; ++ot) {
                bfrag bv = *(const bfrag*)&XT[(ot * 16 + ln16) * 136 + j0 + quad * 8];
                oacc[rt][ot] = __builtin_amdgcn_mfma_f32_16x16x32_bf16(a2, bv, oacc[rt][ot], 0, 0, 0);
            }
        }
    }

#pragma unroll
    for (int rt = 0; rt < 2; ++rt) {
        int i_base = (wave + rt * 4) * 16;
#pragma unroll
        for (int r = 0; r < 4; ++r) {
            size_t grow = (chunkrow + i_base + quad * 4 + r) * HD;
#pragma unroll
            for (int ot = 0; ot < 5; ++ot)
                oin[grow + ot * 16 + ln16] = oacc[rt][ot][r];
        }
    }

    __syncthreads();
    for (int u = t; u < HD * CC; u += 256) {
        int e = u >> 7, j = u & 127;
        int idx = e * 136 + j;
        XT[idx] = f2bf(bf2f(XT[idx]) * sqk[j]);
    }
    __syncthreads();

    float* kvout = ckv + (size_t)bk * (HD * HD);
    for (int p = wave; p < 25; p += 4) {
        int me = p / 5, ne = p - me * 5;
        f4 c = (f4)0.f;
#pragma unroll
        for (int ks = 0; ks < 4; ++ks) {
            bfrag av = *(const bfrag*)&XT[(me * 16 + ln16) * 136 + ks * 32 + quad * 8];
            bfrag bv = *(const bfrag*)&XT[(ne * 16 + ln16) * 136 + ks * 32 + quad * 8];
            c = __builtin_amdgcn_mfma_f32_16x16x32_bf16(av, bv, c, 0, 0, 0);
        }
#pragma unroll
        for (int r = 0; r < 4; ++r)
            kvout[(me * 16 + quad * 4 + r) * HD + ne * 16 + ln16] = c[r];
    }
}

// ---------------------------------------------------------------------------
// Kernel 3: in-place decay prefix-scan over chunk KVs.
__global__ __launch_bounds__(256) void k_scan(float* __restrict__ kv,
                                              const float* __restrict__ slopes) {
    int idx = blockIdx.x * 256 + threadIdx.x;
    int bh  = idx / (HD * HD);
    int ed  = idx - bh * (HD * HD);
    float bd = expf(-slopes[bh & 7] * (float)CC);
    size_t base = (size_t)bh * NC * (HD * HD) + ed;
    float st = 0.f;
#pragma unroll
    for (int n = 0; n < NC; ++n) {
        size_t p = base + (size_t)n * (HD * HD);
        float cv = kv[p];
        kv[p] = st;
        st = bd * st + cv;
    }
}

// ---------------------------------------------------------------------------
// Kernel 4: inter-chunk term via bf16 MFMA, fused + intra + residual + LN.
__global__ __launch_bounds__(256) void k_attn_b(const float* __restrict__ hdn_in,
                                                const float* __restrict__ oin,
                                                const float* __restrict__ kvs,
                                                const float* __restrict__ res,
                                                const float* __restrict__ slopes,
                                                const float* __restrict__ g,
                                                const float* __restrict__ be,
                                                float* __restrict__ hdn_out) {
    __shared__ ushortT Qs[CC * 104];     // 128 rows x (96 k, padded stride 104)
    __shared__ ushortT KVT[80 * 104];    // 80 d-rows x (96 e, padded stride 104)

    int t    = threadIdx.x;
    int wave = t >> 6, lane = t & 63;
    int qd   = lane >> 4, ln16 = lane & 15;
    int bk = blockIdx.x;
    int bh = bk >> 4;
    int n  = bk & 15;
    float sl = slopes[bh & 7];

    size_t chunkrow = (size_t)bh * SS + (size_t)n * CC;
    const float* xb = hdn_in + chunkrow * HD;
    const float* KV = kvs + ((size_t)bh * NC + n) * (HD * HD);

    for (int u = t; u < CC * HD; u += 256) {
        int i = u / HD, c = u - i * HD;
        Qs[i * 104 + c] = f2bf(xb[u]);
    }
    for (int u = t; u < CC * 16; u += 256) {
        int i = u >> 4, c = u & 15;
        Qs[i * 104 + 80 + c] = 0;
    }
    for (int u = t; u < HD * HD; u += 256) {
        int e = u / HD, d = u - e * HD;
        KVT[d * 104 + e] = f2bf(KV[u]);
    }
    for (int u = t; u < HD * 16; u += 256) {
        int d = u >> 4, e = u & 15;
        KVT[d * 104 + 80 + e] = 0;
    }
    __syncthreads();

    int m0 = wave * 32;
    bfrag a[2][3];
#pragma unroll
    for (int rt = 0; rt < 2; ++rt)
#pragma unroll
        for (int ks = 0; ks < 3; ++ks)
            a[rt][ks] = *(const bfrag*)&Qs[(m0 + rt * 16 + ln16) * 104 + ks * 32 + qd * 8];

    f4 acc[2][5];
#pragma unroll
    for (int ot = 0; ot < 5; ++ot) {
#pragma unroll
        for (int rt = 0; rt < 2; ++rt) acc[rt][ot] = (f4)0.f;
#pragma unroll
        for (int ks = 0; ks < 3; ++ks) {
            bfrag b = *(const bfrag*)&KVT[(ot * 16 + ln16) * 104 + ks * 32 + qd * 8];
#pragma unroll
            for (int rt = 0; rt < 2; ++rt)
                acc[rt][ot] = __builtin_amdgcn_mfma_f32_16x16x32_bf16(a[rt][ks], b, acc[rt][ot], 0, 0, 0);
        }
    }

#pragma unroll
    for (int rt = 0; rt < 2; ++rt) {
#pragma unroll
        for (int r = 0; r < 4; ++r) {
            int i = m0 + rt * 16 + qd * 4 + r;
            float qdec = expf(-sl * (float)i);
            size_t grow = (chunkrow + i) * HD;
            float tv[5];
            float s = 0.f, sq = 0.f;
#pragma unroll
            for (int ot = 0; ot < 5; ++ot) {
                int col = ot * 16 + ln16;
                tv[ot] = oin[grow + col] + qdec * acc[rt][ot][r] + res[grow + col];
                s += tv[ot]; sq += tv[ot] * tv[ot];
            }
#pragma unroll
            for (int o = 8; o; o >>= 1) { s += __shfl_xor(s, o); sq += __shfl_xor(sq, o); }
            float m    = s * (1.f / 80.f);
            float var  = sq * (1.f / 80.f) - m * m;
            float rstd = rsqrtf(var + 1e-5f);
#pragma unroll
            for (int ot = 0; ot < 5; ++ot) {
                int col = ot * 16 + ln16;
                hdn_out[grow + col] = (tv[ot] - m) * rstd * g[col] + be[col];
            }
        }
    }
}

// ---------------------------------------------------------------------------
// Kernel 5: FFN via bf16 MFMA, 128 rows/block, vectorized staging,
// 3 barriers per hidden chunk. Hs aliases the W1 tile (wave-private rows, so
// no barrier between Hs writes and GEMM2 reads — same-wave ds ordering).
__global__ __launch_bounds__(256, 2) void k_ffn(const float* __restrict__ hdn_in,
                                                const ushortT* __restrict__ W1T,
                                                const float* __restrict__ b1,
                                                const ushortT* __restrict__ W2T,
                                                const float* __restrict__ b2,
                                                const float* __restrict__ res,
                                                const float* __restrict__ g,
                                                const float* __restrict__ be,
                                                float* __restrict__ hdn_out) {
    __shared__ ushortT Xs[128 * 104];    // 26.6 KB: X tile, K padded 80->96
    __shared__ ushortT WH[128 * 104];    // 26.6 KB: W1 tile (rows 0..95) / Hs alias (128 rows)
    __shared__ ushortT W2s[80 * 104];    // 16.6 KB
    // total 69.9 KB -> 2 blocks/CU

    int t    = threadIdx.x;
    int wave = t >> 6, lane = t & 63;
    int qd   = lane >> 4, ln16 = lane & 15;
    size_t rowbase = (size_t)blockIdx.x * 128;

    // stage X vectorized: 128 rows x 20 float4; convert to bf16, ds_write_b64
    {
        const f4* xin = (const f4*)(hdn_in + rowbase * HD);
        for (int u = t; u < 128 * 20; u += 256) {
            int i = u / 20, c4 = u - i * 20;
            f4 v = xin[u];
            ushortT tmp[4];
#pragma unroll
            for (int z = 0; z < 4; ++z) tmp[z] = f2bf(v[z]);
            *(double*)&Xs[i * 104 + c4 * 4] = *(double*)tmp;   // 8B write
        }
        for (int u = t; u < 128 * 16; u += 256) {
            int i = u >> 4, c = u & 15;
            Xs[i * 104 + 80 + c] = 0;
        }
    }

    f4 acc[2][5];
#pragma unroll
    for (int rt = 0; rt < 2; ++rt)
#pragma unroll
        for (int ot = 0; ot < 5; ++ot) acc[rt][ot] = (f4)0.f;

    const u4* W1T16 = (const u4*)W1T;    // 480 rows x 12 u4
    const u4* W2T16 = (const u4*)W2T;    // 80 rows x 60 u4
    u4* WH16  = (u4*)WH;                 // row stride 13 u4 (=104 ushort)
    u4* W2s16 = (u4*)W2s;

    for (int jt = 0; jt < DH; jt += 96) {
        __syncthreads();   // protects Xs (iter 0) / WH+W2s from previous iter reads
        // stage W1 chunk rows jt..jt+95 (96 x 12 u4) and W2 chunk (80 x 12 u4)
        for (int u = t; u < 96 * 12; u += 256) {
            int n = u / 12, k = u - n * 12;
            WH16[n * 13 + k] = W1T16[(size_t)(jt + n) * 12 + k];
        }
        for (int u = t; u < 80 * 12; u += 256) {
            int n = u / 12, k = u - n * 12;
            W2s16[n * 13 + k] = W2T16[(size_t)n * 60 + (jt >> 3) + k];
        }
        __syncthreads();

        // GEMM1: H chunk = X @ W1c. Each wave: 2 m-tiles (rows wave*32..+31)
        f4 hc[2][6];
#pragma unroll
        for (int rt = 0; rt < 2; ++rt)
#pragma unroll
            for (int nt = 0; nt < 6; ++nt) hc[rt][nt] = (f4)0.f;
#pragma unroll
        for (int ks = 0; ks < 3; ++ks) {
            bfrag a0 = *(const bfrag*)&Xs[((wave * 2 + 0) * 16 + ln16) * 104 + ks * 32 + qd * 8];
            bfrag a1 = *(const bfrag*)&Xs[((wave * 2 + 1) * 16 + ln16) * 104 + ks * 32 + qd * 8];
#pragma unroll
            for (int nt = 0; nt < 6; ++nt) {
                bfrag b = *(const bfrag*)&WH[(nt * 16 + ln16) * 104 + ks * 32 + qd * 8];
                hc[0][nt] = __builtin_amdgcn_mfma_f32_16x16x32_bf16(a0, b, hc[0][nt], 0, 0, 0);
                hc[1][nt] = __builtin_amdgcn_mfma_f32_16x16x32_bf16(a1, b, hc[1][nt], 0, 0, 0);
            }
        }
        __syncthreads();   // all waves done reading W1 tile (WH) before Hs overwrite

        // leaky-relu + bf16 -> Hs (aliases WH; rows wave-private)
#pragma unroll
        for (int rt = 0; rt < 2; ++rt) {
            int mrow = (wave * 2 + rt) * 16 + qd * 4;
#pragma unroll
            for (int nt = 0; nt < 6; ++nt) {
                float bv = b1[jt + nt * 16 + ln16];
#pragma unroll
                for (int r = 0; r < 4; ++r) {
                    float v = hc[rt][nt][r] + bv;
                    v = (v > 0.f) ? v : 0.01f * v;
                    WH[(mrow + r) * 104 + nt * 16 + ln16] = f2bf(v);
                }
            }
        }
        // GEMM2: acc += H chunk @ W2c (no barrier: Hs rows written by this wave)
#pragma unroll
        for (int ks = 0; ks < 3; ++ks) {
            bfrag a0 = *(const bfrag*)&WH[((wave * 2 + 0) * 16 + ln16) * 104 + ks * 32 + qd * 8];
            bfrag a1 = *(const bfrag*)&WH[((wave * 2 + 1) * 16 + ln16) * 104 + ks * 32 + qd * 8];
#pragma unroll
            for (int ot = 0; ot < 5; ++ot) {
                bfrag b = *(const bfrag*)&W2s[(ot * 16 + ln16) * 104 + ks * 32 + qd * 8];
                acc[0][ot] = __builtin_amdgcn_mfma_f32_16x16x32_bf16(a0, b, acc[0][ot], 0, 0, 0);
                acc[1][ot] = __builtin_amdgcn_mfma_f32_16x16x32_bf16(a1, b, acc[1][ot], 0, 0, 0);
            }
        }
    }

    // epilogue: + b2 + residual, LN per row (C-layout: row=qd*4+r, col=ot*16+ln16)
#pragma unroll
    for (int rt = 0; rt < 2; ++rt) {
        int mbase = (wave * 2 + rt) * 16 + qd * 4;
#pragma unroll
        for (int r = 0; r < 4; ++r) {
            size_t row = rowbase + mbase + r;
            float tv[5];
            float s = 0.f, sq = 0.f;
#pragma unroll
            for (int ot = 0; ot < 5; ++ot) {
                int col = ot * 16 + ln16;
                tv[ot] = acc[rt][ot][r] + b2[col] + res[row * HD + col];
                s += tv[ot]; sq += tv[ot] * tv[ot];
            }
#pragma unroll
            for (int o = 8; o; o >>= 1) { s += __shfl_xor(s, o); sq += __shfl_xor(sq, o); }
            float m    = s * (1.f / 80.f);
            float var  = sq * (1.f / 80.f) - m * m;
            float rstd = rsqrtf(var + 1e-5f);
#pragma unroll
            for (int ot = 0; ot < 5; ++ot) {
                int col = ot * 16 + ln16;
                hdn_out[row * HD + col] = (tv[ot] - m) * rstd * g[col] + be[col];
            }
        }
    }
}

// ---------------------------------------------------------------------------
// Kernel 6: mean over heads -> (B, S, HD)
__global__ __launch_bounds__(256) void k_mean(const float* __restrict__ hdn,
                                              float* __restrict__ out) {
    int idx = blockIdx.x * 256 + threadIdx.x;
    int b   = idx / (SS * HD);
    int sd  = idx - b * (SS * HD);
    float s = 0.f;
#pragma unroll
    for (int h = 0; h < HH; ++h)
        s += hdn[((size_t)(b * HH + h)) * (SS * HD) + sd];
    out[idx] = s * 0.125f;
}

// ---------------------------------------------------------------------------
extern "C" void kernel_launch(void* const* d_in, const int* in_sizes, int n_in,
                              void* d_out, int out_size, void* d_ws, size_t ws_size,
                              hipStream_t stream) {
    (void)in_sizes; (void)n_in; (void)out_size; (void)ws_size;
    const float* x      = (const float*)d_in[0];
    const float* W1     = (const float*)d_in[1];
    const float* b1     = (const float*)d_in[2];
    const float* W2     = (const float*)d_in[3];
    const float* b2     = (const float*)d_in[4];
    const float* gamma  = (const float*)d_in[5];
    const float* beta   = (const float*)d_in[6];
    const float* slopes = (const float*)d_in[7];
    float* out = (float*)d_out;
    float* ws  = (float*)d_ws;

    float* res = ws;                 // 5,242,880 floats
    float* hdn = ws + ROWSZ;         // 5,242,880
    float* oin = ws + 2 * ROWSZ;     // 5,242,880
    float* kv  = ws + 3 * ROWSZ;     // 32*16*6400 = 3,276,800

    // bf16 transposed weights live in d_out scratch (k_mean overwrites it last)
    ushortT* W1T = (ushortT*)d_out;         // 480*96
    ushortT* W2T = W1T + 480 * 96;          // 80*480

    k_prep<<<(480 * 96 + 80 * 480 + 255) / 256, 256, 0, stream>>>(W1, W2, W1T, W2T);
    k_ln0<<<NROW / 4, 256, 0, stream>>>(x, gamma, beta, hdn, res);
    for (int it = 0; it < 2; ++it) {
        k_attn_a<<<BB * HH * NC, 256, 0, stream>>>(hdn, slopes, oin, kv);
        k_scan<<<(BB * HH * HD * HD) / 256, 256, 0, stream>>>(kv, slopes);
        k_attn_b<<<BB * HH * NC, 256, 0, stream>>>(hdn, oin, kv, res, slopes, gamma, beta, hdn);
        k_ffn<<<NROW / 128, 256, 0, stream>>>(hdn, W1T, b1, W2T, b2, res, gamma, beta, hdn);
    }
    k_mean<<<(BB * SS * HD) / 256, 256, 0, stream>>>(hdn, out);
}

// Round 10
// 232.671 us; speedup vs baseline: 5.1739x; 1.0352x over previous
//
#include <hip/hip_runtime.h>
#include <hip/hip_bf16.h>

// Problem constants
#define BB 4
#define HH 8
#define SS 2048
#define HD 80
#define CC 128
#define NC 16
#define DH 480           // MULT*HD
#define NROW (BB*HH*SS)  // 65536
#define ROWSZ ((size_t)NROW * HD)  // 5,242,880 floats per tensor buffer

typedef unsigned short ushortT;
typedef __attribute__((ext_vector_type(8))) short bfrag;   // 8 bf16 = 4 VGPRs
typedef __attribute__((ext_vector_type(4))) float f4;
typedef __attribute__((ext_vector_type(4))) unsigned int u4;

__device__ __forceinline__ ushortT f2bf(float f) {
    __hip_bfloat16 h = __float2bfloat16(f);   // RNE
    ushortT u; __builtin_memcpy(&u, &h, 2); return u;
}
__device__ __forceinline__ float bf2f(ushortT u) {
    unsigned int x = ((unsigned int)u) << 16;
    float f; __builtin_memcpy(&f, &x, 4); return f;
}

// ---------------------------------------------------------------------------
// Kernel 0: prep — transpose + bf16-cast W1 (-> W1T[480][96], K zero-padded)
// and W2 (-> W2T[80][480]). Outputs live in d_out tail (k_mean overwrites last).
__global__ __launch_bounds__(256) void k_prep(const float* __restrict__ W1,
                                              const float* __restrict__ W2,
                                              ushortT* __restrict__ W1T,
                                              ushortT* __restrict__ W2T) {
    int idx = blockIdx.x * 256 + threadIdx.x;
    if (idx < 480 * 96) {
        int n = idx / 96, k = idx - n * 96;
        float v = (k < HD) ? W1[k * DH + n] : 0.f;
        W1T[idx] = f2bf(v);
    } else if (idx < 480 * 96 + 80 * 480) {
        int j = idx - 480 * 96;
        int n = j / DH, k = j - n * DH;
        W2T[j] = f2bf(W2[k * HD + n]);
    }
}

// ---------------------------------------------------------------------------
// Kernel 1: first LN. hdn stored as bf16 (every consumer casts to bf16 anyway
// — bit-identical); res stays fp32 (used in fp32 epilogue adds).
__global__ __launch_bounds__(256) void k_ln0(const float* __restrict__ x,
                                             const float* __restrict__ g,
                                             const float* __restrict__ be,
                                             ushortT* __restrict__ hdnb,
                                             float* __restrict__ res) {
    int row  = blockIdx.x * 4 + (threadIdx.x >> 6);
    int lane = threadIdx.x & 63;
    const float* xr = x + (size_t)row * HD;
    float v0 = xr[lane];
    float v1 = (lane < 16) ? xr[64 + lane] : 0.f;
    float s  = v0 + v1;
    float sq = v0 * v0 + v1 * v1;
#pragma unroll
    for (int o = 32; o; o >>= 1) { s += __shfl_xor(s, o); sq += __shfl_xor(sq, o); }
    float m    = s * (1.f / 80.f);
    float var  = sq * (1.f / 80.f) - m * m;
    float rstd = rsqrtf(var + 1e-5f);
    size_t base = (size_t)row * HD;
    float y0 = (v0 - m) * rstd * g[lane] + be[lane];
    hdnb[base + lane] = f2bf(y0); res[base + lane] = y0;
    if (lane < 16) {
        float y1 = (v1 - m) * rstd * g[64 + lane] + be[64 + lane];
        hdnb[base + 64 + lane] = f2bf(y1); res[base + 64 + lane] = y1;
    }
}

// ---------------------------------------------------------------------------
// Kernel 2: per-chunk intra attention + chunk KV, all via bf16 MFMA.
// Input hdn is bf16 now (scalar staging, same structure as proven-green r5).
__global__ __launch_bounds__(256) void k_attn_a(const ushortT* __restrict__ hdn,
                                                const float* __restrict__ slopes,
                                                float* __restrict__ oin,
                                                float* __restrict__ ckv) {
    __shared__ ushortT Xs[CC * 104];   // 128 rows x 96(k-pad, stride 104)
    __shared__ ushortT SC[CC * 40];    // 128 rows x 32(pad 40) score block, A-layout
    __shared__ ushortT XT[HD * 136];   // 80 d-rows x 128 j (stride 136)
    __shared__ float dec[CC];          // exp(-sl*delta)
    __shared__ float sqk[CC];          // sqrt(kd[j]) = exp(-0.5*sl*(128-j))

    int t    = threadIdx.x;
    int wave = t >> 6, lane = t & 63;
    int quad = lane >> 4, ln16 = lane & 15;
    int bk = blockIdx.x;
    int bh = bk >> 4;
    int n  = bk & 15;
    float sl = slopes[bh & 7];

    size_t chunkrow = (size_t)bh * SS + (size_t)n * CC;
    const ushortT* xb = hdn + chunkrow * HD;

    if (t < CC) {
        dec[t] = expf(-sl * (float)t);
        sqk[t] = expf(-0.5f * sl * (float)(CC - t));
    }
    for (int u = t; u < CC * HD; u += 256) {
        int i = u / HD, c = u - i * HD;
        ushortT v = xb[u];
        Xs[i * 104 + c] = v;
        XT[c * 136 + i] = v;
    }
    for (int u = t; u < CC * 16; u += 256) {
        int i = u >> 4, c = u & 15;
        Xs[i * 104 + 80 + c] = 0;
    }
    __syncthreads();

    bfrag a[2][3];
#pragma unroll
    for (int rt = 0; rt < 2; ++rt) {
        int mt = wave + rt * 4;
#pragma unroll
        for (int ks = 0; ks < 3; ++ks)
            a[rt][ks] = *(const bfrag*)&Xs[(mt * 16 + ln16) * 104 + ks * 32 + quad * 8];
    }

    f4 oacc[2][5];
#pragma unroll
    for (int rt = 0; rt < 2; ++rt)
#pragma unroll
        for (int ot = 0; ot < 5; ++ot) oacc[rt][ot] = (f4)0.f;

    for (int jt = 0; jt < 4; ++jt) {
        if (wave + 4 < 2 * jt) continue;
        int j0 = jt * 32;
        bfrag bq[2][3];
#pragma unroll
        for (int nt = 0; nt < 2; ++nt)
#pragma unroll
            for (int ks = 0; ks < 3; ++ks)
                bq[nt][ks] = *(const bfrag*)&Xs[(j0 + nt * 16 + ln16) * 104 + ks * 32 + quad * 8];

#pragma unroll
        for (int rt = 0; rt < 2; ++rt) {
            int mt = wave + rt * 4;
            if (mt < 2 * jt) continue;
            int i_base = mt * 16;
            f4 c0 = (f4)0.f, c1 = (f4)0.f;
#pragma unroll
            for (int ks = 0; ks < 3; ++ks) {
                c0 = __builtin_amdgcn_mfma_f32_16x16x32_bf16(a[rt][ks], bq[0][ks], c0, 0, 0, 0);
                c1 = __builtin_amdgcn_mfma_f32_16x16x32_bf16(a[rt][ks], bq[1][ks], c1, 0, 0, 0);
            }
#pragma unroll
            for (int r = 0; r < 4; ++r) {
                int i = i_base + quad * 4 + r;
                int d0 = i - (j0 + ln16);
                int d1 = d0 - 16;
                float f0 = (d0 >= 0) ? dec[d0] : 0.f;
                float f1 = (d1 >= 0) ? dec[d1] : 0.f;
                SC[i * 40 + ln16]      = f2bf(c0[r] * f0);
                SC[i * 40 + 16 + ln16] = f2bf(c1[r] * f1);
            }
            bfrag a2 = *(const bfrag*)&SC[(i_base + ln16) * 40 + quad * 8];
#pragma unroll
            for (int ot = 0; ot < 5; ++ot) {
                bfrag bv = *(const bfrag*)&XT[(ot * 16 + ln16) * 136 + j0 + quad * 8];
                oacc[rt][ot] = __builtin_amdgcn_mfma_f32_16x16x32_bf16(a2, bv, oacc[rt][ot], 0, 0, 0);
            }
        }
    }

#pragma unroll
    for (int rt = 0; rt < 2; ++rt) {
        int i_base = (wave + rt * 4) * 16;
#pragma unroll
        for (int r = 0; r < 4; ++r) {
            size_t grow = (chunkrow + i_base + quad * 4 + r) * HD;
#pragma unroll
            for (int ot = 0; ot < 5; ++ot)
                oin[grow + ot * 16 + ln16] = oacc[rt][ot][r];
        }
    }

    __syncthreads();
    for (int u = t; u < HD * CC; u += 256) {
        int e = u >> 7, j = u & 127;
        int idx = e * 136 + j;
        XT[idx] = f2bf(bf2f(XT[idx]) * sqk[j]);
    }
    __syncthreads();

    float* kvout = ckv + (size_t)bk * (HD * HD);
    for (int p = wave; p < 25; p += 4) {
        int me = p / 5, ne = p - me * 5;
        f4 c = (f4)0.f;
#pragma unroll
        for (int ks = 0; ks < 4; ++ks) {
            bfrag av = *(const bfrag*)&XT[(me * 16 + ln16) * 136 + ks * 32 + quad * 8];
            bfrag bv = *(const bfrag*)&XT[(ne * 16 + ln16) * 136 + ks * 32 + quad * 8];
            c = __builtin_amdgcn_mfma_f32_16x16x32_bf16(av, bv, c, 0, 0, 0);
        }
#pragma unroll
        for (int r = 0; r < 4; ++r)
            kvout[(me * 16 + quad * 4 + r) * HD + ne * 16 + ln16] = c[r];
    }
}

// ---------------------------------------------------------------------------
// Kernel 3: in-place decay prefix-scan over chunk KVs.
__global__ __launch_bounds__(256) void k_scan(float* __restrict__ kv,
                                              const float* __restrict__ slopes) {
    int idx = blockIdx.x * 256 + threadIdx.x;
    int bh  = idx / (HD * HD);
    int ed  = idx - bh * (HD * HD);
    float bd = expf(-slopes[bh & 7] * (float)CC);
    size_t base = (size_t)bh * NC * (HD * HD) + ed;
    float st = 0.f;
#pragma unroll
    for (int n = 0; n < NC; ++n) {
        size_t p = base + (size_t)n * (HD * HD);
        float cv = kv[p];
        kv[p] = st;
        st = bd * st + cv;
    }
}

// ---------------------------------------------------------------------------
// Kernel 4: inter-chunk term via bf16 MFMA, fused + intra + residual + LN.
// hdn in/out are bf16 now; Q staging is a pure u4 copy (pattern proven green
// in k_ffn weight staging). Output bf16 (consumer k_ffn casts anyway).
__global__ __launch_bounds__(256) void k_attn_b(const ushortT* __restrict__ hdn_in,
                                                const float* __restrict__ oin,
                                                const float* __restrict__ kvs,
                                                const float* __restrict__ res,
                                                const float* __restrict__ slopes,
                                                const float* __restrict__ g,
                                                const float* __restrict__ be,
                                                ushortT* __restrict__ hdn_out) {
    __shared__ ushortT Qs[CC * 104];     // 128 rows x (96 k, padded stride 104)
    __shared__ ushortT KVT[80 * 104];    // 80 d-rows x (96 e, padded stride 104)

    int t    = threadIdx.x;
    int wave = t >> 6, lane = t & 63;
    int qd   = lane >> 4, ln16 = lane & 15;
    int bk = blockIdx.x;
    int bh = bk >> 4;
    int n  = bk & 15;
    float sl = slopes[bh & 7];

    size_t chunkrow = (size_t)bh * SS + (size_t)n * CC;
    const ushortT* xb = hdn_in + chunkrow * HD;
    const float* KV = kvs + ((size_t)bh * NC + n) * (HD * HD);

    // Q staging: rows are 10 u4 (160B) each; Qs stride 104 ushorts = 13 u4.
    {
        const u4* xin = (const u4*)xb;
        u4* Qs4 = (u4*)Qs;
        for (int u = t; u < CC * 10; u += 256) {
            int i = u / 10, c = u - i * 10;
            Qs4[i * 13 + c] = xin[u];
        }
        for (int u = t; u < CC * 16; u += 256) {
            int i = u >> 4, c = u & 15;
            Qs[i * 104 + 80 + c] = 0;
        }
    }
    for (int u = t; u < HD * HD; u += 256) {
        int e = u / HD, d = u - e * HD;
        KVT[d * 104 + e] = f2bf(KV[u]);
    }
    for (int u = t; u < HD * 16; u += 256) {
        int d = u >> 4, e = u & 15;
        KVT[d * 104 + 80 + e] = 0;
    }
    __syncthreads();

    int m0 = wave * 32;
    bfrag a[2][3];
#pragma unroll
    for (int rt = 0; rt < 2; ++rt)
#pragma unroll
        for (int ks = 0; ks < 3; ++ks)
            a[rt][ks] = *(const bfrag*)&Qs[(m0 + rt * 16 + ln16) * 104 + ks * 32 + qd * 8];

    f4 acc[2][5];
#pragma unroll
    for (int ot = 0; ot < 5; ++ot) {
#pragma unroll
        for (int rt = 0; rt < 2; ++rt) acc[rt][ot] = (f4)0.f;
#pragma unroll
        for (int ks = 0; ks < 3; ++ks) {
            bfrag b = *(const bfrag*)&KVT[(ot * 16 + ln16) * 104 + ks * 32 + qd * 8];
#pragma unroll
            for (int rt = 0; rt < 2; ++rt)
                acc[rt][ot] = __builtin_amdgcn_mfma_f32_16x16x32_bf16(a[rt][ks], b, acc[rt][ot], 0, 0, 0);
        }
    }

#pragma unroll
    for (int rt = 0; rt < 2; ++rt) {
#pragma unroll
        for (int r = 0; r < 4; ++r) {
            int i = m0 + rt * 16 + qd * 4 + r;
            float qdec = expf(-sl * (float)i);
            size_t grow = (chunkrow + i) * HD;
            float tv[5];
            float s = 0.f, sq = 0.f;
#pragma unroll
            for (int ot = 0; ot < 5; ++ot) {
                int col = ot * 16 + ln16;
                tv[ot] = oin[grow + col] + qdec * acc[rt][ot][r] + res[grow + col];
                s += tv[ot]; sq += tv[ot] * tv[ot];
            }
#pragma unroll
            for (int o = 8; o; o >>= 1) { s += __shfl_xor(s, o); sq += __shfl_xor(sq, o); }
            float m    = s * (1.f / 80.f);
            float var  = sq * (1.f / 80.f) - m * m;
            float rstd = rsqrtf(var + 1e-5f);
#pragma unroll
            for (int ot = 0; ot < 5; ++ot) {
                int col = ot * 16 + ln16;
                hdn_out[grow + col] = f2bf((tv[ot] - m) * rstd * g[col] + be[col]);
            }
        }
    }
}

// ---------------------------------------------------------------------------
// Kernel 5: FFN via bf16 MFMA, 128 rows/block. Input bf16 (u4-copy staging).
// Output: bf16 (iter 0, consumed by attn kernels) or fp32 (iter 1, k_mean).
__global__ __launch_bounds__(256, 2) void k_ffn(const ushortT* __restrict__ hdn_in,
                                                const ushortT* __restrict__ W1T,
                                                const float* __restrict__ b1,
                                                const ushortT* __restrict__ W2T,
                                                const float* __restrict__ b2,
                                                const float* __restrict__ res,
                                                const float* __restrict__ g,
                                                const float* __restrict__ be,
                                                ushortT* __restrict__ outb,
                                                float* __restrict__ outf,
                                                int write_f32) {
    __shared__ ushortT Xs[128 * 104];    // 26.6 KB: X tile, K padded 80->96
    __shared__ ushortT WH[128 * 104];    // 26.6 KB: W1 tile (rows 0..95) / Hs alias
    __shared__ ushortT W2s[80 * 104];    // 16.6 KB
    // total 69.9 KB -> 2 blocks/CU

    int t    = threadIdx.x;
    int wave = t >> 6, lane = t & 63;
    int qd   = lane >> 4, ln16 = lane & 15;
    size_t rowbase = (size_t)blockIdx.x * 128;

    // stage X: pure u4 copy (rows = 10 u4 of bf16; Xs stride 13 u4)
    {
        const u4* xin = (const u4*)(hdn_in + rowbase * HD);
        u4* Xs4 = (u4*)Xs;
        for (int u = t; u < 128 * 10; u += 256) {
            int i = u / 10, c = u - i * 10;
            Xs4[i * 13 + c] = xin[u];
        }
        for (int u = t; u < 128 * 16; u += 256) {
            int i = u >> 4, c = u & 15;
            Xs[i * 104 + 80 + c] = 0;
        }
    }

    f4 acc[2][5];
#pragma unroll
    for (int rt = 0; rt < 2; ++rt)
#pragma unroll
        for (int ot = 0; ot < 5; ++ot) acc[rt][ot] = (f4)0.f;

    const u4* W1T16 = (const u4*)W1T;    // 480 rows x 12 u4
    const u4* W2T16 = (const u4*)W2T;    // 80 rows x 60 u4
    u4* WH16  = (u4*)WH;                 // row stride 13 u4 (=104 ushort)
    u4* W2s16 = (u4*)W2s;

    for (int jt = 0; jt < DH; jt += 96) {
        __syncthreads();   // protects Xs (iter 0) / WH+W2s from previous iter reads
        for (int u = t; u < 96 * 12; u += 256) {
            int n = u / 12, k = u - n * 12;
            WH16[n * 13 + k] = W1T16[(size_t)(jt + n) * 12 + k];
        }
        for (int u = t; u < 80 * 12; u += 256) {
            int n = u / 12, k = u - n * 12;
            W2s16[n * 13 + k] = W2T16[(size_t)n * 60 + (jt >> 3) + k];
        }
        __syncthreads();

        // GEMM1: H chunk = X @ W1c. Each wave: 2 m-tiles (rows wave*32..+31)
        f4 hc[2][6];
#pragma unroll
        for (int rt = 0; rt < 2; ++rt)
#pragma unroll
            for (int nt = 0; nt < 6; ++nt) hc[rt][nt] = (f4)0.f;
#pragma unroll
        for (int ks = 0; ks < 3; ++ks) {
            bfrag a0 = *(const bfrag*)&Xs[((wave * 2 + 0) * 16 + ln16) * 104 + ks * 32 + qd * 8];
            bfrag a1 = *(const bfrag*)&Xs[((wave * 2 + 1) * 16 + ln16) * 104 + ks * 32 + qd * 8];
#pragma unroll
            for (int nt = 0; nt < 6; ++nt) {
                bfrag b = *(const bfrag*)&WH[(nt * 16 + ln16) * 104 + ks * 32 + qd * 8];
                hc[0][nt] = __builtin_amdgcn_mfma_f32_16x16x32_bf16(a0, b, hc[0][nt], 0, 0, 0);
                hc[1][nt] = __builtin_amdgcn_mfma_f32_16x16x32_bf16(a1, b, hc[1][nt], 0, 0, 0);
            }
        }
        __syncthreads();   // all waves done reading W1 tile (WH) before Hs overwrite

        // leaky-relu + bf16 -> Hs (aliases WH; rows wave-private)
#pragma unroll
        for (int rt = 0; rt < 2; ++rt) {
            int mrow = (wave * 2 + rt) * 16 + qd * 4;
#pragma unroll
            for (int nt = 0; nt < 6; ++nt) {
                float bv = b1[jt + nt * 16 + ln16];
#pragma unroll
                for (int r = 0; r < 4; ++r) {
                    float v = hc[rt][nt][r] + bv;
                    v = (v > 0.f) ? v : 0.01f * v;
                    WH[(mrow + r) * 104 + nt * 16 + ln16] = f2bf(v);
                }
            }
        }
        // GEMM2: acc += H chunk @ W2c (no barrier: Hs rows written by this wave)
#pragma unroll
        for (int ks = 0; ks < 3; ++ks) {
            bfrag a0 = *(const bfrag*)&WH[((wave * 2 + 0) * 16 + ln16) * 104 + ks * 32 + qd * 8];
            bfrag a1 = *(const bfrag*)&WH[((wave * 2 + 1) * 16 + ln16) * 104 + ks * 32 + qd * 8];
#pragma unroll
            for (int ot = 0; ot < 5; ++ot) {
                bfrag b = *(const bfrag*)&W2s[(ot * 16 + ln16) * 104 + ks * 32 + qd * 8];
                acc[0][ot] = __builtin_amdgcn_mfma_f32_16x16x32_bf16(a0, b, acc[0][ot], 0, 0, 0);
                acc[1][ot] = __builtin_amdgcn_mfma_f32_16x16x32_bf16(a1, b, acc[1][ot], 0, 0, 0);
            }
        }
    }

    // epilogue: + b2 + residual, LN per row (C-layout: row=qd*4+r, col=ot*16+ln16)
#pragma unroll
    for (int rt = 0; rt < 2; ++rt) {
        int mbase = (wave * 2 + rt) * 16 + qd * 4;
#pragma unroll
        for (int r = 0; r < 4; ++r) {
            size_t row = rowbase + mbase + r;
            float tv[5];
            float s = 0.f, sq = 0.f;
#pragma unroll
            for (int ot = 0; ot < 5; ++ot) {
                int col = ot * 16 + ln16;
                tv[ot] = acc[rt][ot][r] + b2[col] + res[row * HD + col];
                s += tv[ot]; sq += tv[ot] * tv[ot];
            }
#pragma unroll
            for (int o = 8; o; o >>= 1) { s += __shfl_xor(s, o); sq += __shfl_xor(sq, o); }
            float m    = s * (1.f / 80.f);
            float var  = sq * (1.f / 80.f) - m * m;
            float rstd = rsqrtf(var + 1e-5f);
            if (write_f32) {
#pragma unroll
                for (int ot = 0; ot < 5; ++ot) {
                    int col = ot * 16 + ln16;
                    outf[row * HD + col] = (tv[ot] - m) * rstd * g[col] + be[col];
                }
            } else {
#pragma unroll
                for (int ot = 0; ot < 5; ++ot) {
                    int col = ot * 16 + ln16;
                    outb[row * HD + col] = f2bf((tv[ot] - m) * rstd * g[col] + be[col]);
                }
            }
        }
    }
}

// ---------------------------------------------------------------------------
// Kernel 6: mean over heads -> (B, S, HD). Reads the fp32 final buffer.
__global__ __launch_bounds__(256) void k_mean(const float* __restrict__ hdn,
                                              float* __restrict__ out) {
    int idx = blockIdx.x * 256 + threadIdx.x;
    int b   = idx / (SS * HD);
    int sd  = idx - b * (SS * HD);
    float s = 0.f;
#pragma unroll
    for (int h = 0; h < HH; ++h)
        s += hdn[((size_t)(b * HH + h)) * (SS * HD) + sd];
    out[idx] = s * 0.125f;
}

// ---------------------------------------------------------------------------
extern "C" void kernel_launch(void* const* d_in, const int* in_sizes, int n_in,
                              void* d_out, int out_size, void* d_ws, size_t ws_size,
                              hipStream_t stream) {
    (void)in_sizes; (void)n_in; (void)out_size; (void)ws_size;
    const float* x      = (const float*)d_in[0];
    const float* W1     = (const float*)d_in[1];
    const float* b1     = (const float*)d_in[2];
    const float* W2     = (const float*)d_in[3];
    const float* b2     = (const float*)d_in[4];
    const float* gamma  = (const float*)d_in[5];
    const float* beta   = (const float*)d_in[6];
    const float* slopes = (const float*)d_in[7];
    float* out = (float*)d_out;
    float* ws  = (float*)d_ws;

    float*   res  = ws;                          // fp32, 5,242,880 floats
    ushortT* hdnb = (ushortT*)(ws + ROWSZ);      // bf16 hdn intermediates
    float*   oin  = ws + 2 * ROWSZ;              // fp32 (precision-critical)
    float*   kv   = ws + 3 * ROWSZ;              // fp32, 3,276,800
    float*   hdnf = ws + 4 * ROWSZ;              // fp32 final (k_mean input)

    // bf16 transposed weights live in d_out scratch (k_mean overwrites it last)
    ushortT* W1T = (ushortT*)d_out;              // 480*96
    ushortT* W2T = W1T + 480 * 96;               // 80*480

    k_prep<<<(480 * 96 + 80 * 480 + 255) / 256, 256, 0, stream>>>(W1, W2, W1T, W2T);
    k_ln0<<<NROW / 4, 256, 0, stream>>>(x, gamma, beta, hdnb, res);
    for (int it = 0; it < 2; ++it) {
        k_attn_a<<<BB * HH * NC, 256, 0, stream>>>(hdnb, slopes, oin, kv);
        k_scan<<<(BB * HH * HD * HD) / 256, 256, 0, stream>>>(kv, slopes);
        k_attn_b<<<BB * HH * NC, 256, 0, stream>>>(hdnb, oin, kv, res, slopes, gamma, beta, hdnb);
        k_ffn<<<NROW / 128, 256, 0, stream>>>(hdnb, W1T, b1, W2T, b2, res, gamma, beta,
                                              hdnb, hdnf, (it == 1) ? 1 : 0);
    }
    k_mean<<<(BB * SS * HD) / 256, 256, 0, stream>>>(hdnf, out);
}